// Round 17
// baseline (250.620 us; speedup 1.0000x reference)
//
#include <hip/hip_runtime.h>

// ---------------------------------------------------------------------------
// 3-layer GCN forward. out[d] = relu( dinv[d]*( sum_{s->d} g[s] + g[d] ) + b ),
// g = (x@W)*dinv stored as OCP fp8 e4m3 scaled by S=256.
// r17: agg1 sliced CORRECTLY: G1 = [2][N][32] fp8 (3.2MB/slice < 4MB per-XCD
// L2); each slice pass runs NPW=2 -> EPW=4 -> full 8-deep pipeline (r14's
// slice failed because EPW=8 broke the pipeline; NPW fixes that). Gathers
// now hit L2 instead of ~40% missing to L3. Same bytes, same lane-work.
// k_agg: NPW nodes/wave (r15). k_mfma: barrier-free direct-A (r13).
// Xb bf16 (r14-verified). CSR: two-level counting sort (r10).
// ---------------------------------------------------------------------------

#define BSH 9                 // 512 nodes per bucket
#define BNODES (1 << BSH)
#define FP8_S 256.0f          // message scale (e4m3: denorm<0.0156, max 448)

typedef __attribute__((ext_vector_type(8))) short bf16x8;
typedef __attribute__((ext_vector_type(4))) float f32x4;
typedef __attribute__((ext_vector_type(2))) float f32x2;

__device__ inline ushort f2bf(float x) {   // round-to-nearest-even f32->bf16
    uint u = __float_as_uint(x);
    return (ushort)((u + 0x7fffu + ((u >> 16) & 1u)) >> 16);
}
__device__ inline unsigned char f2fp8(float v) {   // f32 -> e4m3 (HW, RNE+sat)
    int p = __builtin_amdgcn_cvt_pk_fp8_f32(v, v, 0, false);
    return (unsigned char)(p & 0xff);
}

// fused: bucket histogram of dst (blocks < HB) + W1/W2/W3 bf16 transpose
__global__ __launch_bounds__(256) void k_pre(
    const int* __restrict__ dst, int* __restrict__ bcnt, int E, int HB,
    const float* __restrict__ W1, const float* __restrict__ W2,
    const float* __restrict__ W3,
    ushort* __restrict__ Wh1, ushort* __restrict__ Wh2,
    ushort* __restrict__ Wh3)
{
    if ((int)blockIdx.x < HB) {
        __shared__ int h[256];
        int t = threadIdx.x;
        h[t] = 0;
        __syncthreads();
        for (int i = blockIdx.x * 256 + t; i < E; i += HB * 256)
            atomicAdd(&h[dst[i] >> BSH], 1);
        __syncthreads();
        if (h[t]) atomicAdd(&bcnt[t], h[t]);
        return;
    }
    int i = (blockIdx.x - HB) * 256 + threadIdx.x;
    if (i < 16384) {                       // W1: 256x64
        int k = i >> 6, n = i & 63;
        Wh1[n * 256 + k] = f2bf(W1[i]);
    } else if (i < 16384 + 2048) {         // W2: 64x32
        int j = i - 16384;
        int k = j >> 5, n = j & 31;
        Wh2[n * 64 + k] = f2bf(W2[j]);
    } else if (i < 16384 + 2048 + 512) {   // W3: 32x16
        int j = i - 18432;
        int k = j >> 4, n = j & 15;
        Wh3[n * 32 + k] = f2bf(W3[j]);
    }
}

// scan bucket counts -> boff (exclusive), init bcur. NB <= 1024.
__global__ __launch_bounds__(1024) void k_bscan(const int* __restrict__ bcnt,
                                                int* __restrict__ boff,
                                                int* __restrict__ bcur, int NB) {
    __shared__ int s[1024];
    int t = threadIdx.x;
    int v = (t < NB) ? bcnt[t] : 0;
    s[t] = v;
    __syncthreads();
    for (int off = 1; off < 1024; off <<= 1) {
        int a = (t >= off) ? s[t - off] : 0;
        __syncthreads();
        s[t] += a;
        __syncthreads();
    }
    if (t < NB) {
        int ex = s[t] - v;
        boff[t] = ex;
        bcur[t] = ex;
    }
    if (t == NB - 1) boff[NB] = s[t];
}

// partition edges into bucket-contiguous packed (local_dst<<23 | src) words.
// LDS reorder: bin chunk bucket-major, write coalesced runs (no 4x write amp).
template <int CH>
__global__ __launch_bounds__(256) void k_part(const int* __restrict__ src,
                                              const int* __restrict__ dst,
                                              int* __restrict__ bcur,
                                              uint* __restrict__ pairs,
                                              int E, int NB) {
    __shared__ uint sval[CH];
    __shared__ unsigned char sbid[CH];     // NB <= 256
    __shared__ int lh[256], lofs[256], lbase[256], cur[256];
    const int t = threadIdx.x;
    const int e0 = blockIdx.x * CH;
    const int n = min(CH, E - e0);

    lh[t] = 0;
    cur[t] = 0;
    __syncthreads();
    for (int i = t; i < n; i += 256) atomicAdd(&lh[dst[e0 + i] >> BSH], 1);
    __syncthreads();
    int v = lh[t];
    lofs[t] = v;
    __syncthreads();
    for (int off = 1; off < 256; off <<= 1) {
        int a = (t >= off) ? lofs[t - off] : 0;
        __syncthreads();
        lofs[t] += a;
        __syncthreads();
    }
    int ex = lofs[t] - v;
    if (v > 0) lbase[t] = atomicAdd(&bcur[t], v);
    __syncthreads();
    lofs[t] = ex;
    __syncthreads();
    for (int i = t; i < n; i += 256) {
        int d = dst[e0 + i];
        int b = d >> BSH;
        int r = atomicAdd(&cur[b], 1);
        int slot = lofs[b] + r;
        sval[slot] = ((uint)(d & (BNODES - 1)) << 23) | (uint)src[e0 + i];
        sbid[slot] = (unsigned char)b;
    }
    __syncthreads();
    for (int i = t; i < n; i += 256) {
        int b = sbid[i];
        pairs[(long)lbase[b] + (i - lofs[b])] = sval[i];
    }
}

// per-bucket: per-node histogram + scan (LDS), emit row_off/dinv, scatter esrc
__global__ __launch_bounds__(1024) void k_bucket(const uint* __restrict__ pairs,
                                                 const int* __restrict__ boff,
                                                 int* __restrict__ row_off,
                                                 float* __restrict__ dinv,
                                                 int* __restrict__ esrc,
                                                 int N, int NB, int E) {
    __shared__ int cnt[BNODES];
    __shared__ int sc[BNODES];
    __shared__ int cur[BNODES];
    const int b = blockIdx.x;
    const int t = threadIdx.x;
    const int base = b << BSH;
    const int nn = min(BNODES, N - base);
    const int ebase = boff[b], eend = boff[b + 1];

    if (t < BNODES) cnt[t] = 0;
    __syncthreads();
    for (int e = ebase + t; e < eend; e += 1024)
        atomicAdd(&cnt[pairs[e] >> 23], 1);
    __syncthreads();
    if (t < BNODES) sc[t] = cnt[t];
    __syncthreads();
    for (int off = 1; off < BNODES; off <<= 1) {
        int a = (t < BNODES && t >= off) ? sc[t - off] : 0;
        __syncthreads();
        if (t < BNODES) sc[t] += a;
        __syncthreads();
    }
    if (t < nn) {
        int ex = sc[t] - cnt[t];
        row_off[base + t] = ebase + ex;
        cur[t] = ex;
        dinv[base + t] = rsqrtf((float)(cnt[t] + 1));
    }
    if (b == NB - 1 && t == 0) row_off[N] = E;
    __syncthreads();
    for (int e = ebase + t; e < eend; e += 1024) {
        uint p = pairs[e];
        int r = atomicAdd(&cur[p >> 23], 1);
        esrc[ebase + r] = (int)(p & 0x7fffffu);
    }
}

// ---------------------------------------------------------------------------
// Barrier-free direct-A MFMA GEMM (single-pass bf16):
// G = fp8( (X[row(n)] @ W) * dinv[n] * S ).
// XBF16: X is bf16 stride-sx. SLICED: write [2][N][32] layout (slice=nt>>1).
// Block = 64 rows (4 waves x 16), W in LDS [OF][K+8] staged once.
// ---------------------------------------------------------------------------
template <int K, int OF, bool XBF16, bool SLICED>
__global__ __launch_bounds__(256) void k_mfma(
    const void* __restrict__ Xv, int sx,
    const int* __restrict__ nodes,          // may be null (identity)
    const ushort* __restrict__ Wh,          // [OF][K] bf16
    const float* __restrict__ dinv,
    unsigned char* __restrict__ G,          // fp8 e4m3, value*S
    int N)
{
    constexpr int LDK = K + 8;
    constexpr int NT = OF / 16;             // MFMA col tiles
    constexpr int NSTEP = K / 32;
    __shared__ ushort Wlds[OF * LDK];

    const int tid = threadIdx.x;
    const int l = tid & 63;
    const int w = tid >> 6;                 // wave id: rows w*16..w*16+15
    const int m0 = blockIdx.x * 64;
    const int lm = l & 15, kg = l >> 4;

#pragma unroll
    for (int i = tid; i < OF * K / 8; i += 256) {
        int n = i / (K / 8), seg = i % (K / 8);
        *reinterpret_cast<uint4*>(&Wlds[n * LDK + seg * 8]) =
            *reinterpret_cast<const uint4*>(Wh + (long)n * K + seg * 8);
    }

    const float* xrf = nullptr;
    const ushort* xrb = nullptr;
    {
        int m = m0 + w * 16 + lm;
        if (m < N) {
            long r = nodes ? (long)nodes[m] : (long)m;
            if (XBF16) xrb = (const ushort*)Xv + r * (long)sx + kg * 8;
            else       xrf = (const float*)Xv + r * (long)sx + kg * 8;
        }
    }

    f32x4 acc[NT];
#pragma unroll
    for (int nt = 0; nt < NT; ++nt) acc[nt] = (f32x4){0.f, 0.f, 0.f, 0.f};

    __syncthreads();   // W staged; K-loop below is barrier-free

#pragma unroll
    for (int s = 0; s < NSTEP; ++s) {
        bf16x8 av = (bf16x8){0, 0, 0, 0, 0, 0, 0, 0};
        if (XBF16) {
            if (xrb) av = *reinterpret_cast<const bf16x8*>(xrb + s * 32);
        } else if (xrf) {
            float4 a0 = *reinterpret_cast<const float4*>(xrf + s * 32);
            float4 a1 = *reinterpret_cast<const float4*>(xrf + s * 32 + 4);
            av[0] = (short)f2bf(a0.x); av[1] = (short)f2bf(a0.y);
            av[2] = (short)f2bf(a0.z); av[3] = (short)f2bf(a0.w);
            av[4] = (short)f2bf(a1.x); av[5] = (short)f2bf(a1.y);
            av[6] = (short)f2bf(a1.z); av[7] = (short)f2bf(a1.w);
        }
#pragma unroll
        for (int nt = 0; nt < NT; ++nt) {
            bf16x8 bv = *reinterpret_cast<bf16x8*>(
                &Wlds[(nt * 16 + lm) * LDK + s * 32 + kg * 8]);
            acc[nt] = __builtin_amdgcn_mfma_f32_16x16x32_bf16(av, bv, acc[nt], 0, 0, 0);
        }
    }

#pragma unroll
    for (int r = 0; r < 4; ++r) {
        int m = m0 + w * 16 + kg * 4 + r;
        if (m < N) {
            float sc = dinv[m] * FP8_S;
#pragma unroll
            for (int nt = 0; nt < NT; ++nt) {
                unsigned char v = f2fp8(acc[nt][r] * sc);
                if (SLICED)
                    G[(long)(nt >> 1) * N * 32 + (long)m * 32 + (nt & 1) * 16 + lm] = v;
                else
                    G[(long)m * OF + nt * 16 + lm] = v;
            }
        }
    }
}

// ---------------------------------------------------------------------------
// CSR aggregation — fp8 payload, NPW nodes per wave (lane groups of 64/NPW).
// WPE = OF/4 lanes/edge, EPW = (64/NPW)/WPE edges in parallel; NPW chosen so
// EPW==4 -> deg~32 fills the full 8-deep pipeline. f32 accumulate via HW
// cvt_pk; epilogue folds 1/S; optional bf16 output.
// ---------------------------------------------------------------------------
#define UNPK4(A, W)                                                        \
    {                                                                      \
        f32x2 _lo = __builtin_amdgcn_cvt_pk_f32_fp8((int)(W), false);      \
        f32x2 _hi = __builtin_amdgcn_cvt_pk_f32_fp8((int)(W), true);       \
        A.x += _lo[0]; A.y += _lo[1]; A.z += _hi[0]; A.w += _hi[1];        \
    }

template <int OF, int OSTRIDE, bool YBF16, int NPW>
__global__ __launch_bounds__(256) void k_agg(
    const int* __restrict__ row_off, const int* __restrict__ esrc,
    const uint* __restrict__ g,      // table row = OF/4 uints (OF fp8 bytes)
    const float* __restrict__ dinv, const float* __restrict__ b,
    void* __restrict__ y, int N)
{
    constexpr int LPN = 64 / NPW;    // lanes per node group
    constexpr int WPE = OF / 4;      // lanes per edge
    constexpr int EPW = LPN / WPE;   // edges in parallel per node
    const int lane = threadIdx.x & 63;
    const int grp = lane / LPN;      // node group within wave
    const int ll  = lane % LPN;
    const int q = ll % WPE;          // feature quad
    const int sub = ll / WPE;        // edge sub-slot
    const int wid = blockIdx.x * (blockDim.x >> 6) + (threadIdx.x >> 6);
    const int n = wid * NPW + grp;
    if (n >= N) return;
    const int start = row_off[n], end = row_off[n + 1];

    float4 ac[4];
#pragma unroll
    for (int u = 0; u < 4; ++u) ac[u] = make_float4(0.f, 0.f, 0.f, 0.f);

    int e = start + sub;
    for (; e + 7 * EPW < end; e += 8 * EPW) {
        int s0[4], s1[4];
#pragma unroll
        for (int u = 0; u < 4; ++u) s0[u] = esrc[e + u * EPW];
#pragma unroll
        for (int u = 0; u < 4; ++u) s1[u] = esrc[e + (4 + u) * EPW];
        uint w0[4], w1[4];
#pragma unroll
        for (int u = 0; u < 4; ++u) w0[u] = g[(long)s0[u] * WPE + q];
#pragma unroll
        for (int u = 0; u < 4; ++u) w1[u] = g[(long)s1[u] * WPE + q];
#pragma unroll
        for (int u = 0; u < 4; ++u) { UNPK4(ac[u], w0[u]); }
#pragma unroll
        for (int u = 0; u < 4; ++u) { UNPK4(ac[u], w1[u]); }
    }
    for (; e + 3 * EPW < end; e += 4 * EPW) {
        int s[4];
        uint w[4];
#pragma unroll
        for (int u = 0; u < 4; ++u) s[u] = esrc[e + u * EPW];
#pragma unroll
        for (int u = 0; u < 4; ++u) w[u] = g[(long)s[u] * WPE + q];
#pragma unroll
        for (int u = 0; u < 4; ++u) { UNPK4(ac[u], w[u]); }
    }
    for (; e < end; e += EPW) {
        uint w = g[(long)esrc[e] * WPE + q];
        UNPK4(ac[0], w);
    }
    float4 a;
    a.x = (ac[0].x + ac[1].x) + (ac[2].x + ac[3].x);
    a.y = (ac[0].y + ac[1].y) + (ac[2].y + ac[3].y);
    a.z = (ac[0].z + ac[1].z) + (ac[2].z + ac[3].z);
    a.w = (ac[0].w + ac[1].w) + (ac[2].w + ac[3].w);
#pragma unroll
    for (int m = WPE; m < LPN; m <<= 1) {   // group-local reduction
        a.x += __shfl_xor(a.x, m, 64);
        a.y += __shfl_xor(a.y, m, 64);
        a.z += __shfl_xor(a.z, m, 64);
        a.w += __shfl_xor(a.w, m, 64);
    }
    if (sub == 0) {
        uint sv = g[(long)n * WPE + q];   // self loop
        UNPK4(a, sv);
        float dvs = dinv[n] * (1.0f / FP8_S);
        float4 bb = *reinterpret_cast<const float4*>(&b[q * 4]);
        float4 o;
        o.x = fmaxf(fmaf(a.x, dvs, bb.x), 0.f);
        o.y = fmaxf(fmaf(a.y, dvs, bb.y), 0.f);
        o.z = fmaxf(fmaf(a.z, dvs, bb.z), 0.f);
        o.w = fmaxf(fmaf(a.w, dvs, bb.w), 0.f);
        if (YBF16) {
            ushort4 ob = {f2bf(o.x), f2bf(o.y), f2bf(o.z), f2bf(o.w)};
            *reinterpret_cast<ushort4*>((ushort*)y + (long)n * OSTRIDE + q * 4) = ob;
        } else {
            *reinterpret_cast<float4*>((float*)y + (long)n * OSTRIDE + q * 4) = o;
        }
    }
}

extern "C" void kernel_launch(void* const* d_in, const int* in_sizes, int n_in,
                              void* d_out, int out_size, void* d_ws, size_t ws_size,
                              hipStream_t stream) {
    const int*   nodes = (const int*)d_in[0];
    const int*   edges = (const int*)d_in[1];
    const float* emb   = (const float*)d_in[2];
    const float* W1    = (const float*)d_in[3];
    const float* b1    = (const float*)d_in[4];
    const float* W2    = (const float*)d_in[5];
    const float* b2    = (const float*)d_in[6];
    const float* W3    = (const float*)d_in[7];
    const float* b3    = (const float*)d_in[8];

    const int N = in_sizes[0];
    const int E = in_sizes[1] / 2;
    const int* src  = edges;
    const int* dstv = edges + E;
    const int NB = (N + BNODES - 1) >> BSH;   // 196 for N=100000

    char* ws = (char*)d_ws;
    size_t off = 0;
    auto alloc = [&](size_t bytes) {
        char* p = ws + off;
        off += (bytes + 255) & ~(size_t)255;
        return p;
    };
    float* dinv    = (float*)alloc((size_t)N * 4);
    int*   row_off = (int*)  alloc((size_t)(N + 1) * 4);
    int*   bcnt    = (int*)  alloc((size_t)(NB + 1) * 4);
    int*   boff    = (int*)  alloc((size_t)(NB + 1) * 4);
    int*   bcur    = (int*)  alloc((size_t)NB * 4);
    int*   esrc    = (int*)  alloc((size_t)E * 4);
    char*  shared_region = alloc((size_t)E * 4);   // pairs u32 (12.8MB) / G1 fp8 (6.4MB)
    uint*  pairs   = (uint*)shared_region;
    unsigned char* G1 = (unsigned char*)shared_region;   // [2][N][32] fp8 slices
    unsigned char* G2 = (unsigned char*)alloc((size_t)N * 32);
    unsigned char* G3 = (unsigned char*)alloc((size_t)N * 16);
    ushort* Xb     = (ushort*)alloc((size_t)N * 64 * 2);  // bf16 activations
    ushort* Wh1 = (ushort*)alloc(16384 * 2);
    ushort* Wh2 = (ushort*)alloc(2048 * 2);
    ushort* Wh3 = (ushort*)alloc(512 * 2);
    float* out     = (float*)d_out;

    // --- CSR build + dinv + W prep ---
    constexpr int CH = 8192;
    constexpr int HB = 1024;              // histogram blocks in k_pre
    const int nch = (E + CH - 1) / CH;
    hipMemsetAsync(bcnt, 0, (size_t)NB * 4, stream);
    hipLaunchKernelGGL(k_pre, dim3(HB + 74), dim3(256), 0, stream,
                       dstv, bcnt, E, HB, W1, W2, W3, Wh1, Wh2, Wh3);
    hipLaunchKernelGGL(k_bscan,  dim3(1), dim3(1024), 0, stream, bcnt, boff, bcur, NB);
    hipLaunchKernelGGL((k_part<CH>), dim3(nch), dim3(256), 0, stream,
                       src, dstv, bcur, pairs, E, NB);
    hipLaunchKernelGGL(k_bucket, dim3(NB), dim3(1024), 0, stream,
                       pairs, boff, row_off, dinv, esrc, N, NB, E);

    const int gb  = (N + 63) / 64;
    const int ab2 = (N + 7) / 8;    // 8 nodes/block (NPW=2)
    const int ab3 = (N + 15) / 16;  // 16 nodes/block (NPW=4)

    // --- layer 1: 256 -> 64 ---  (G1 overwrites pairs; dead after k_bucket)
    hipLaunchKernelGGL((k_mfma<256, 64, false, true>), dim3(gb), dim3(256), 0, stream,
                       emb, 256, nodes, Wh1, dinv, G1, N);
    // agg1: 2 slice passes, each table 3.2MB (per-XCD L2-resident), NPW=2
    for (int sl = 0; sl < 2; ++sl)
        hipLaunchKernelGGL((k_agg<32, 64, true, 2>), dim3(ab2), dim3(256), 0, stream,
                           row_off, esrc,
                           (const uint*)(G1 + (size_t)sl * N * 32),
                           dinv, b1 + sl * 32, Xb + sl * 32, N);
    // --- layer 2: 64 -> 32 ---
    hipLaunchKernelGGL((k_mfma<64, 32, true, false>), dim3(gb), dim3(256), 0, stream,
                       Xb, 64, (const int*)nullptr, Wh2, dinv, G2, N);
    hipLaunchKernelGGL((k_agg<32, 64, true, 2>), dim3(ab2), dim3(256), 0, stream,
                       row_off, esrc, (const uint*)G2, dinv, b2, Xb, N);
    // --- layer 3: 32 -> 16 ---
    hipLaunchKernelGGL((k_mfma<32, 16, true, false>), dim3(gb), dim3(256), 0, stream,
                       Xb, 64, (const int*)nullptr, Wh3, dinv, G3, N);
    hipLaunchKernelGGL((k_agg<16, 16, false, 4>), dim3(ab3), dim3(256), 0, stream,
                       row_off, esrc, (const uint*)G3, dinv, b3, out, N);
}

// Round 18
// 225.668 us; speedup vs baseline: 1.1106x; 1.1106x over previous
//
#include <hip/hip_runtime.h>

// ---------------------------------------------------------------------------
// 3-layer GCN forward. out[d] = relu( dinv[d]*( sum_{s->d} g[s] + g[d] ) + b ),
// g = (x@W)*dinv stored as OCP fp8 e4m3 scaled by S=256, row-major [N][OF].
// r18: slice dead (r14/r17 both regressed). k_agg gathers uint2 = 8 fp8/lane:
// with fp8 rows this keeps 1 cache line/edge (r11's uint2-of-bf16 was 2) while
// HALVING wave-instructions per edge (agg was ~50% VALUBusy = issue-bound)
// and doubling lines-in-flight per gather instr. NPW re-tuned for EPW=4 ->
// full 8-deep pipeline at deg~32: agg1 NPW=2, agg2 NPW=4, agg3 NPW=8.
// k_mfma: barrier-free direct-A (r13). Xb bf16 (r14-verified). CSR: r10.
// ---------------------------------------------------------------------------

#define BSH 9                 // 512 nodes per bucket
#define BNODES (1 << BSH)
#define FP8_S 256.0f          // message scale (e4m3: denorm<0.0156, max 448)

typedef __attribute__((ext_vector_type(8))) short bf16x8;
typedef __attribute__((ext_vector_type(4))) float f32x4;
typedef __attribute__((ext_vector_type(2))) float f32x2;

__device__ inline ushort f2bf(float x) {   // round-to-nearest-even f32->bf16
    uint u = __float_as_uint(x);
    return (ushort)((u + 0x7fffu + ((u >> 16) & 1u)) >> 16);
}
__device__ inline unsigned char f2fp8(float v) {   // f32 -> e4m3 (HW, RNE+sat)
    int p = __builtin_amdgcn_cvt_pk_fp8_f32(v, v, 0, false);
    return (unsigned char)(p & 0xff);
}

// fused: bucket histogram of dst (blocks < HB) + W1/W2/W3 bf16 transpose
__global__ __launch_bounds__(256) void k_pre(
    const int* __restrict__ dst, int* __restrict__ bcnt, int E, int HB,
    const float* __restrict__ W1, const float* __restrict__ W2,
    const float* __restrict__ W3,
    ushort* __restrict__ Wh1, ushort* __restrict__ Wh2,
    ushort* __restrict__ Wh3)
{
    if ((int)blockIdx.x < HB) {
        __shared__ int h[256];
        int t = threadIdx.x;
        h[t] = 0;
        __syncthreads();
        for (int i = blockIdx.x * 256 + t; i < E; i += HB * 256)
            atomicAdd(&h[dst[i] >> BSH], 1);
        __syncthreads();
        if (h[t]) atomicAdd(&bcnt[t], h[t]);
        return;
    }
    int i = (blockIdx.x - HB) * 256 + threadIdx.x;
    if (i < 16384) {                       // W1: 256x64
        int k = i >> 6, n = i & 63;
        Wh1[n * 256 + k] = f2bf(W1[i]);
    } else if (i < 16384 + 2048) {         // W2: 64x32
        int j = i - 16384;
        int k = j >> 5, n = j & 31;
        Wh2[n * 64 + k] = f2bf(W2[j]);
    } else if (i < 16384 + 2048 + 512) {   // W3: 32x16
        int j = i - 18432;
        int k = j >> 4, n = j & 15;
        Wh3[n * 32 + k] = f2bf(W3[j]);
    }
}

// scan bucket counts -> boff (exclusive), init bcur. NB <= 1024.
__global__ __launch_bounds__(1024) void k_bscan(const int* __restrict__ bcnt,
                                                int* __restrict__ boff,
                                                int* __restrict__ bcur, int NB) {
    __shared__ int s[1024];
    int t = threadIdx.x;
    int v = (t < NB) ? bcnt[t] : 0;
    s[t] = v;
    __syncthreads();
    for (int off = 1; off < 1024; off <<= 1) {
        int a = (t >= off) ? s[t - off] : 0;
        __syncthreads();
        s[t] += a;
        __syncthreads();
    }
    if (t < NB) {
        int ex = s[t] - v;
        boff[t] = ex;
        bcur[t] = ex;
    }
    if (t == NB - 1) boff[NB] = s[t];
}

// partition edges into bucket-contiguous packed (local_dst<<23 | src) words.
// LDS reorder: bin chunk bucket-major, write coalesced runs (no 4x write amp).
template <int CH>
__global__ __launch_bounds__(256) void k_part(const int* __restrict__ src,
                                              const int* __restrict__ dst,
                                              int* __restrict__ bcur,
                                              uint* __restrict__ pairs,
                                              int E, int NB) {
    __shared__ uint sval[CH];
    __shared__ unsigned char sbid[CH];     // NB <= 256
    __shared__ int lh[256], lofs[256], lbase[256], cur[256];
    const int t = threadIdx.x;
    const int e0 = blockIdx.x * CH;
    const int n = min(CH, E - e0);

    lh[t] = 0;
    cur[t] = 0;
    __syncthreads();
    for (int i = t; i < n; i += 256) atomicAdd(&lh[dst[e0 + i] >> BSH], 1);
    __syncthreads();
    int v = lh[t];
    lofs[t] = v;
    __syncthreads();
    for (int off = 1; off < 256; off <<= 1) {
        int a = (t >= off) ? lofs[t - off] : 0;
        __syncthreads();
        lofs[t] += a;
        __syncthreads();
    }
    int ex = lofs[t] - v;
    if (v > 0) lbase[t] = atomicAdd(&bcur[t], v);
    __syncthreads();
    lofs[t] = ex;
    __syncthreads();
    for (int i = t; i < n; i += 256) {
        int d = dst[e0 + i];
        int b = d >> BSH;
        int r = atomicAdd(&cur[b], 1);
        int slot = lofs[b] + r;
        sval[slot] = ((uint)(d & (BNODES - 1)) << 23) | (uint)src[e0 + i];
        sbid[slot] = (unsigned char)b;
    }
    __syncthreads();
    for (int i = t; i < n; i += 256) {
        int b = sbid[i];
        pairs[(long)lbase[b] + (i - lofs[b])] = sval[i];
    }
}

// per-bucket: per-node histogram + scan (LDS), emit row_off/dinv, scatter esrc
__global__ __launch_bounds__(1024) void k_bucket(const uint* __restrict__ pairs,
                                                 const int* __restrict__ boff,
                                                 int* __restrict__ row_off,
                                                 float* __restrict__ dinv,
                                                 int* __restrict__ esrc,
                                                 int N, int NB, int E) {
    __shared__ int cnt[BNODES];
    __shared__ int sc[BNODES];
    __shared__ int cur[BNODES];
    const int b = blockIdx.x;
    const int t = threadIdx.x;
    const int base = b << BSH;
    const int nn = min(BNODES, N - base);
    const int ebase = boff[b], eend = boff[b + 1];

    if (t < BNODES) cnt[t] = 0;
    __syncthreads();
    for (int e = ebase + t; e < eend; e += 1024)
        atomicAdd(&cnt[pairs[e] >> 23], 1);
    __syncthreads();
    if (t < BNODES) sc[t] = cnt[t];
    __syncthreads();
    for (int off = 1; off < BNODES; off <<= 1) {
        int a = (t < BNODES && t >= off) ? sc[t - off] : 0;
        __syncthreads();
        if (t < BNODES) sc[t] += a;
        __syncthreads();
    }
    if (t < nn) {
        int ex = sc[t] - cnt[t];
        row_off[base + t] = ebase + ex;
        cur[t] = ex;
        dinv[base + t] = rsqrtf((float)(cnt[t] + 1));
    }
    if (b == NB - 1 && t == 0) row_off[N] = E;
    __syncthreads();
    for (int e = ebase + t; e < eend; e += 1024) {
        uint p = pairs[e];
        int r = atomicAdd(&cur[p >> 23], 1);
        esrc[ebase + r] = (int)(p & 0x7fffffu);
    }
}

// ---------------------------------------------------------------------------
// Barrier-free direct-A MFMA GEMM (single-pass bf16):
// G[n][0..OF) = fp8( (X[row(n)] @ W) * dinv[n] * S ), row-major stride OF.
// XBF16: X is bf16 stride-sx (load fragment directly, no cvt).
// Block = 64 rows (4 waves x 16), W in LDS [OF][K+8] staged once.
// ---------------------------------------------------------------------------
template <int K, int OF, bool XBF16>
__global__ __launch_bounds__(256) void k_mfma(
    const void* __restrict__ Xv, int sx,
    const int* __restrict__ nodes,          // may be null (identity)
    const ushort* __restrict__ Wh,          // [OF][K] bf16
    const float* __restrict__ dinv,
    unsigned char* __restrict__ G,          // fp8 e4m3, stride OF, value*S
    int N)
{
    constexpr int LDK = K + 8;
    constexpr int NT = OF / 16;             // MFMA col tiles
    constexpr int NSTEP = K / 32;
    __shared__ ushort Wlds[OF * LDK];

    const int tid = threadIdx.x;
    const int l = tid & 63;
    const int w = tid >> 6;                 // wave id: rows w*16..w*16+15
    const int m0 = blockIdx.x * 64;
    const int lm = l & 15, kg = l >> 4;

#pragma unroll
    for (int i = tid; i < OF * K / 8; i += 256) {
        int n = i / (K / 8), seg = i % (K / 8);
        *reinterpret_cast<uint4*>(&Wlds[n * LDK + seg * 8]) =
            *reinterpret_cast<const uint4*>(Wh + (long)n * K + seg * 8);
    }

    const float* xrf = nullptr;
    const ushort* xrb = nullptr;
    {
        int m = m0 + w * 16 + lm;
        if (m < N) {
            long r = nodes ? (long)nodes[m] : (long)m;
            if (XBF16) xrb = (const ushort*)Xv + r * (long)sx + kg * 8;
            else       xrf = (const float*)Xv + r * (long)sx + kg * 8;
        }
    }

    f32x4 acc[NT];
#pragma unroll
    for (int nt = 0; nt < NT; ++nt) acc[nt] = (f32x4){0.f, 0.f, 0.f, 0.f};

    __syncthreads();   // W staged; K-loop below is barrier-free

#pragma unroll
    for (int s = 0; s < NSTEP; ++s) {
        bf16x8 av = (bf16x8){0, 0, 0, 0, 0, 0, 0, 0};
        if (XBF16) {
            if (xrb) av = *reinterpret_cast<const bf16x8*>(xrb + s * 32);
        } else if (xrf) {
            float4 a0 = *reinterpret_cast<const float4*>(xrf + s * 32);
            float4 a1 = *reinterpret_cast<const float4*>(xrf + s * 32 + 4);
            av[0] = (short)f2bf(a0.x); av[1] = (short)f2bf(a0.y);
            av[2] = (short)f2bf(a0.z); av[3] = (short)f2bf(a0.w);
            av[4] = (short)f2bf(a1.x); av[5] = (short)f2bf(a1.y);
            av[6] = (short)f2bf(a1.z); av[7] = (short)f2bf(a1.w);
        }
#pragma unroll
        for (int nt = 0; nt < NT; ++nt) {
            bf16x8 bv = *reinterpret_cast<bf16x8*>(
                &Wlds[(nt * 16 + lm) * LDK + s * 32 + kg * 8]);
            acc[nt] = __builtin_amdgcn_mfma_f32_16x16x32_bf16(av, bv, acc[nt], 0, 0, 0);
        }
    }

#pragma unroll
    for (int r = 0; r < 4; ++r) {
        int m = m0 + w * 16 + kg * 4 + r;
        if (m < N) {
            float sc = dinv[m] * FP8_S;
#pragma unroll
            for (int nt = 0; nt < NT; ++nt)
                G[(long)m * OF + nt * 16 + lm] = f2fp8(acc[nt][r] * sc);
        }
    }
}

// ---------------------------------------------------------------------------
// CSR aggregation — fp8 payload, uint2 gather (8 fp8/lane, 1 line/edge).
// WPE = OF/8 lanes/edge; NPW nodes/wave; EPW = (64/NPW)/WPE = 4 -> full
// 8-deep pipeline at deg~32. 2 accumulator sets of float[8] (16 VGPR).
// f32 accumulate via HW cvt_pk; epilogue folds 1/S; optional bf16 output.
// ---------------------------------------------------------------------------
#define UNPK8(A, W)                                                        \
    {                                                                      \
        f32x2 _p0 = __builtin_amdgcn_cvt_pk_f32_fp8((int)(W).x, false);    \
        f32x2 _p1 = __builtin_amdgcn_cvt_pk_f32_fp8((int)(W).x, true);     \
        f32x2 _p2 = __builtin_amdgcn_cvt_pk_f32_fp8((int)(W).y, false);    \
        f32x2 _p3 = __builtin_amdgcn_cvt_pk_f32_fp8((int)(W).y, true);     \
        A[0] += _p0[0]; A[1] += _p0[1]; A[2] += _p1[0]; A[3] += _p1[1];    \
        A[4] += _p2[0]; A[5] += _p2[1]; A[6] += _p3[0]; A[7] += _p3[1];    \
    }

template <int OF, int OSTRIDE, bool YBF16, int NPW>
__global__ __launch_bounds__(256) void k_agg(
    const int* __restrict__ row_off, const int* __restrict__ esrc,
    const uint2* __restrict__ g,     // table row = OF/8 uint2 (OF fp8 bytes)
    const float* __restrict__ dinv, const float* __restrict__ b,
    void* __restrict__ y, int N)
{
    constexpr int LPN = 64 / NPW;    // lanes per node group
    constexpr int WPE = OF / 8;      // lanes per edge (uint2 each)
    constexpr int EPW = LPN / WPE;   // edges in parallel per node (= 4)
    static_assert(EPW == 4, "geometry: want EPW==4 for the 8-deep pipeline");
    const int lane = threadIdx.x & 63;
    const int grp = lane / LPN;      // node group within wave
    const int ll  = lane % LPN;
    const int q = ll % WPE;          // feature octet
    const int sub = ll / WPE;        // edge sub-slot 0..3
    const int wid = blockIdx.x * (blockDim.x >> 6) + (threadIdx.x >> 6);
    const int n = wid * NPW + grp;
    if (n >= N) return;
    const int start = row_off[n], end = row_off[n + 1];

    float a0[8], a1[8];
#pragma unroll
    for (int j = 0; j < 8; ++j) { a0[j] = 0.f; a1[j] = 0.f; }

    int e = start + sub;
    for (; e + 7 * EPW < end; e += 8 * EPW) {
        int s[8];
#pragma unroll
        for (int u = 0; u < 8; ++u) s[u] = esrc[e + u * EPW];
        uint2 w[8];
#pragma unroll
        for (int u = 0; u < 8; ++u) w[u] = g[(long)s[u] * WPE + q];
#pragma unroll
        for (int u = 0; u < 8; u += 2) { UNPK8(a0, w[u]); UNPK8(a1, w[u + 1]); }
    }
    for (; e + 3 * EPW < end; e += 4 * EPW) {
        int s[4];
#pragma unroll
        for (int u = 0; u < 4; ++u) s[u] = esrc[e + u * EPW];
        uint2 w[4];
#pragma unroll
        for (int u = 0; u < 4; ++u) w[u] = g[(long)s[u] * WPE + q];
        UNPK8(a0, w[0]); UNPK8(a1, w[1]); UNPK8(a0, w[2]); UNPK8(a1, w[3]);
    }
    for (; e < end; e += EPW) {
        uint2 w = g[(long)esrc[e] * WPE + q];
        UNPK8(a0, w);
    }

    float tot[8];
#pragma unroll
    for (int j = 0; j < 8; ++j) tot[j] = a0[j] + a1[j];
#pragma unroll
    for (int m = WPE; m < LPN; m <<= 1)   // group-local reduction
#pragma unroll
        for (int j = 0; j < 8; ++j) tot[j] += __shfl_xor(tot[j], m, 64);

    if (sub == 0) {
        uint2 sv = g[(long)n * WPE + q];   // self loop
        float sl[8] = {0.f, 0.f, 0.f, 0.f, 0.f, 0.f, 0.f, 0.f};
        UNPK8(sl, sv);
        float dvs = dinv[n] * (1.0f / FP8_S);
        float4 b0 = *reinterpret_cast<const float4*>(b + q * 8);
        float4 b1 = *reinterpret_cast<const float4*>(b + q * 8 + 4);
        float bb[8] = {b0.x, b0.y, b0.z, b0.w, b1.x, b1.y, b1.z, b1.w};
        float o[8];
#pragma unroll
        for (int j = 0; j < 8; ++j)
            o[j] = fmaxf(fmaf(tot[j] + sl[j], dvs, bb[j]), 0.f);
        if (YBF16) {
            uint4 ob;
            ob.x = (uint)f2bf(o[0]) | ((uint)f2bf(o[1]) << 16);
            ob.y = (uint)f2bf(o[2]) | ((uint)f2bf(o[3]) << 16);
            ob.z = (uint)f2bf(o[4]) | ((uint)f2bf(o[5]) << 16);
            ob.w = (uint)f2bf(o[6]) | ((uint)f2bf(o[7]) << 16);
            *reinterpret_cast<uint4*>((ushort*)y + (long)n * OSTRIDE + q * 8) = ob;
        } else {
            float4 o0 = {o[0], o[1], o[2], o[3]};
            float4 o1 = {o[4], o[5], o[6], o[7]};
            *reinterpret_cast<float4*>((float*)y + (long)n * OSTRIDE + q * 8) = o0;
            *reinterpret_cast<float4*>((float*)y + (long)n * OSTRIDE + q * 8 + 4) = o1;
        }
    }
}

extern "C" void kernel_launch(void* const* d_in, const int* in_sizes, int n_in,
                              void* d_out, int out_size, void* d_ws, size_t ws_size,
                              hipStream_t stream) {
    const int*   nodes = (const int*)d_in[0];
    const int*   edges = (const int*)d_in[1];
    const float* emb   = (const float*)d_in[2];
    const float* W1    = (const float*)d_in[3];
    const float* b1    = (const float*)d_in[4];
    const float* W2    = (const float*)d_in[5];
    const float* b2    = (const float*)d_in[6];
    const float* W3    = (const float*)d_in[7];
    const float* b3    = (const float*)d_in[8];

    const int N = in_sizes[0];
    const int E = in_sizes[1] / 2;
    const int* src  = edges;
    const int* dstv = edges + E;
    const int NB = (N + BNODES - 1) >> BSH;   // 196 for N=100000

    char* ws = (char*)d_ws;
    size_t off = 0;
    auto alloc = [&](size_t bytes) {
        char* p = ws + off;
        off += (bytes + 255) & ~(size_t)255;
        return p;
    };
    float* dinv    = (float*)alloc((size_t)N * 4);
    int*   row_off = (int*)  alloc((size_t)(N + 1) * 4);
    int*   bcnt    = (int*)  alloc((size_t)(NB + 1) * 4);
    int*   boff    = (int*)  alloc((size_t)(NB + 1) * 4);
    int*   bcur    = (int*)  alloc((size_t)NB * 4);
    int*   esrc    = (int*)  alloc((size_t)E * 4);
    char*  shared_region = alloc((size_t)E * 4);   // pairs u32 (12.8MB) / G1 fp8 (6.4MB)
    uint*  pairs   = (uint*)shared_region;
    unsigned char* G1 = (unsigned char*)shared_region;   // [N][64] fp8
    unsigned char* G2 = (unsigned char*)alloc((size_t)N * 32);
    unsigned char* G3 = (unsigned char*)alloc((size_t)N * 16);
    ushort* Xb     = (ushort*)alloc((size_t)N * 64 * 2);  // bf16 activations
    ushort* Wh1 = (ushort*)alloc(16384 * 2);
    ushort* Wh2 = (ushort*)alloc(2048 * 2);
    ushort* Wh3 = (ushort*)alloc(512 * 2);
    float* out     = (float*)d_out;

    // --- CSR build + dinv + W prep ---
    constexpr int CH = 8192;
    constexpr int HB = 1024;              // histogram blocks in k_pre
    const int nch = (E + CH - 1) / CH;
    hipMemsetAsync(bcnt, 0, (size_t)NB * 4, stream);
    hipLaunchKernelGGL(k_pre, dim3(HB + 74), dim3(256), 0, stream,
                       dstv, bcnt, E, HB, W1, W2, W3, Wh1, Wh2, Wh3);
    hipLaunchKernelGGL(k_bscan,  dim3(1), dim3(1024), 0, stream, bcnt, boff, bcur, NB);
    hipLaunchKernelGGL((k_part<CH>), dim3(nch), dim3(256), 0, stream,
                       src, dstv, bcur, pairs, E, NB);
    hipLaunchKernelGGL(k_bucket, dim3(NB), dim3(1024), 0, stream,
                       pairs, boff, row_off, dinv, esrc, N, NB, E);

    const int gb  = (N + 63) / 64;
    const int ab1 = (N + 7) / 8;    // NPW=2: 8 nodes/block
    const int ab2 = (N + 15) / 16;  // NPW=4: 16 nodes/block
    const int ab3 = (N + 31) / 32;  // NPW=8: 32 nodes/block

    // --- layer 1: 256 -> 64 ---  (G1 overwrites pairs; dead after k_bucket)
    hipLaunchKernelGGL((k_mfma<256, 64, false>), dim3(gb), dim3(256), 0, stream,
                       emb, 256, nodes, Wh1, dinv, G1, N);
    hipLaunchKernelGGL((k_agg<64, 64, true, 2>), dim3(ab1), dim3(256), 0, stream,
                       row_off, esrc, (const uint2*)G1, dinv, b1, Xb, N);
    // --- layer 2: 64 -> 32 ---
    hipLaunchKernelGGL((k_mfma<64, 32, true>), dim3(gb), dim3(256), 0, stream,
                       Xb, 64, (const int*)nullptr, Wh2, dinv, G2, N);
    hipLaunchKernelGGL((k_agg<32, 64, true, 4>), dim3(ab2), dim3(256), 0, stream,
                       row_off, esrc, (const uint2*)G2, dinv, b2, Xb, N);
    // --- layer 3: 32 -> 16 ---
    hipLaunchKernelGGL((k_mfma<32, 16, true>), dim3(gb), dim3(256), 0, stream,
                       Xb, 64, (const int*)nullptr, Wh3, dinv, G3, N);
    hipLaunchKernelGGL((k_agg<16, 16, false, 8>), dim3(ab3), dim3(256), 0, stream,
                       row_off, esrc, (const uint2*)G3, dinv, b3, out, N);
}

// Round 19
// 212.436 us; speedup vs baseline: 1.1797x; 1.0623x over previous
//
#include <hip/hip_runtime.h>

// ---------------------------------------------------------------------------
// 3-layer GCN forward. out[d] = relu( dinv[d]*( sum_{s->d} g[s] + g[d] ) + b ),
// g = (x@W)*dinv stored as OCP fp8 e4m3 scaled by S=256, row-major [N][OF].
// r19: CSR-chain barrier surgery. k_part/k_bucket prefix scans rewritten as
// wave-level shfl_up scans (2 barriers instead of 16/18); k_part widened to
// 512 threads (same LDS, 2x waves/CU for the streaming passes).
// k_agg: uint2 fp8 gather, NPW-tuned EPW=4 8-deep pipeline (r18).
// k_mfma: barrier-free direct-A (r13). Xb bf16 (r14). CSR sort: r10 scheme.
// ---------------------------------------------------------------------------

#define BSH 9                 // 512 nodes per bucket
#define BNODES (1 << BSH)
#define FP8_S 256.0f          // message scale (e4m3: denorm<0.0156, max 448)

typedef __attribute__((ext_vector_type(8))) short bf16x8;
typedef __attribute__((ext_vector_type(4))) float f32x4;
typedef __attribute__((ext_vector_type(2))) float f32x2;

__device__ inline ushort f2bf(float x) {   // round-to-nearest-even f32->bf16
    uint u = __float_as_uint(x);
    return (ushort)((u + 0x7fffu + ((u >> 16) & 1u)) >> 16);
}
__device__ inline unsigned char f2fp8(float v) {   // f32 -> e4m3 (HW, RNE+sat)
    int p = __builtin_amdgcn_cvt_pk_fp8_f32(v, v, 0, false);
    return (unsigned char)(p & 0xff);
}
__device__ inline int wave_incl_scan(int v, int lane) {  // 64-lane inclusive
    int sc = v;
#pragma unroll
    for (int d = 1; d < 64; d <<= 1) {
        int u = __shfl_up(sc, d, 64);
        if (lane >= d) sc += u;
    }
    return sc;
}

// fused: bucket histogram of dst (blocks < HB) + W1/W2/W3 bf16 transpose
__global__ __launch_bounds__(256) void k_pre(
    const int* __restrict__ dst, int* __restrict__ bcnt, int E, int HB,
    const float* __restrict__ W1, const float* __restrict__ W2,
    const float* __restrict__ W3,
    ushort* __restrict__ Wh1, ushort* __restrict__ Wh2,
    ushort* __restrict__ Wh3)
{
    if ((int)blockIdx.x < HB) {
        __shared__ int h[256];
        int t = threadIdx.x;
        h[t] = 0;
        __syncthreads();
        for (int i = blockIdx.x * 256 + t; i < E; i += HB * 256)
            atomicAdd(&h[dst[i] >> BSH], 1);
        __syncthreads();
        if (h[t]) atomicAdd(&bcnt[t], h[t]);
        return;
    }
    int i = (blockIdx.x - HB) * 256 + threadIdx.x;
    if (i < 16384) {                       // W1: 256x64
        int k = i >> 6, n = i & 63;
        Wh1[n * 256 + k] = f2bf(W1[i]);
    } else if (i < 16384 + 2048) {         // W2: 64x32
        int j = i - 16384;
        int k = j >> 5, n = j & 31;
        Wh2[n * 64 + k] = f2bf(W2[j]);
    } else if (i < 16384 + 2048 + 512) {   // W3: 32x16
        int j = i - 18432;
        int k = j >> 4, n = j & 15;
        Wh3[n * 32 + k] = f2bf(W3[j]);
    }
}

// scan bucket counts -> boff (exclusive), init bcur. NB <= 1024.
__global__ __launch_bounds__(1024) void k_bscan(const int* __restrict__ bcnt,
                                                int* __restrict__ boff,
                                                int* __restrict__ bcur, int NB) {
    __shared__ int s[1024];
    int t = threadIdx.x;
    int v = (t < NB) ? bcnt[t] : 0;
    s[t] = v;
    __syncthreads();
    for (int off = 1; off < 1024; off <<= 1) {
        int a = (t >= off) ? s[t - off] : 0;
        __syncthreads();
        s[t] += a;
        __syncthreads();
    }
    if (t < NB) {
        int ex = s[t] - v;
        boff[t] = ex;
        bcur[t] = ex;
    }
    if (t == NB - 1) boff[NB] = s[t];
}

// partition edges into bucket-contiguous packed (local_dst<<23 | src) words.
// LDS reorder (coalesced runs); wave-scan for the 256-bucket prefix.
template <int CH>
__global__ __launch_bounds__(512) void k_part(const int* __restrict__ src,
                                              const int* __restrict__ dst,
                                              int* __restrict__ bcur,
                                              uint* __restrict__ pairs,
                                              int E, int NB) {
    __shared__ uint sval[CH];
    __shared__ unsigned char sbid[CH];     // NB <= 256
    __shared__ int lh[256], lofs[256], lbase[256], cur[256];
    __shared__ int wsum[4];
    const int t = threadIdx.x;             // 0..511
    const int lane = t & 63, wv = t >> 6;
    const int e0 = blockIdx.x * CH;
    const int n = min(CH, E - e0);

    if (t < 256) { lh[t] = 0; cur[t] = 0; }
    __syncthreads();
    for (int i = t; i < n; i += 512) atomicAdd(&lh[dst[e0 + i] >> BSH], 1);
    __syncthreads();
    int v = 0, sc = 0;
    if (t < 256) {
        v = lh[t];
        sc = wave_incl_scan(v, lane);
        if (lane == 63) wsum[wv] = sc;
    }
    __syncthreads();
    if (t < 256) {
        int pre = 0;
#pragma unroll
        for (int w2 = 0; w2 < 4; ++w2) if (w2 < wv) pre += wsum[w2];
        lofs[t] = pre + sc - v;            // exclusive prefix
        if (v > 0) lbase[t] = atomicAdd(&bcur[t], v);
    }
    __syncthreads();
    for (int i = t; i < n; i += 512) {
        int d = dst[e0 + i];
        int b = d >> BSH;
        int r = atomicAdd(&cur[b], 1);
        int slot = lofs[b] + r;
        sval[slot] = ((uint)(d & (BNODES - 1)) << 23) | (uint)src[e0 + i];
        sbid[slot] = (unsigned char)b;
    }
    __syncthreads();
    for (int i = t; i < n; i += 512) {
        int b = sbid[i];
        pairs[(long)lbase[b] + (i - lofs[b])] = sval[i];
    }
}

// per-bucket: per-node histogram + wave-scan (2 barriers), emit row_off/dinv,
// scatter esrc
__global__ __launch_bounds__(1024) void k_bucket(const uint* __restrict__ pairs,
                                                 const int* __restrict__ boff,
                                                 int* __restrict__ row_off,
                                                 float* __restrict__ dinv,
                                                 int* __restrict__ esrc,
                                                 int N, int NB, int E) {
    __shared__ int cnt[BNODES];
    __shared__ int cur[BNODES];
    __shared__ int wsum[8];
    const int b = blockIdx.x;
    const int t = threadIdx.x;
    const int lane = t & 63, wv = t >> 6;
    const int base = b << BSH;
    const int nn = min(BNODES, N - base);
    const int ebase = boff[b], eend = boff[b + 1];

    if (t < BNODES) cnt[t] = 0;
    __syncthreads();
    for (int e = ebase + t; e < eend; e += 1024)
        atomicAdd(&cnt[pairs[e] >> 23], 1);
    __syncthreads();
    int v = 0, sc = 0;
    if (t < BNODES) {
        v = cnt[t];
        sc = wave_incl_scan(v, lane);
        if (lane == 63) wsum[wv] = sc;
    }
    __syncthreads();
    if (t < nn) {
        int pre = 0;
#pragma unroll
        for (int w2 = 0; w2 < 8; ++w2) if (w2 < wv) pre += wsum[w2];
        int ex = pre + sc - v;             // exclusive prefix
        row_off[base + t] = ebase + ex;
        cur[t] = ex;
        dinv[base + t] = rsqrtf((float)(v + 1));
    }
    if (b == NB - 1 && t == 0) row_off[N] = E;
    __syncthreads();
    for (int e = ebase + t; e < eend; e += 1024) {
        uint p = pairs[e];
        int r = atomicAdd(&cur[p >> 23], 1);
        esrc[ebase + r] = (int)(p & 0x7fffffu);
    }
}

// ---------------------------------------------------------------------------
// Barrier-free direct-A MFMA GEMM (single-pass bf16):
// G[n][0..OF) = fp8( (X[row(n)] @ W) * dinv[n] * S ), row-major stride OF.
// XBF16: X is bf16 stride-sx (load fragment directly, no cvt).
// Block = 64 rows (4 waves x 16), W in LDS [OF][K+8] staged once.
// ---------------------------------------------------------------------------
template <int K, int OF, bool XBF16>
__global__ __launch_bounds__(256) void k_mfma(
    const void* __restrict__ Xv, int sx,
    const int* __restrict__ nodes,          // may be null (identity)
    const ushort* __restrict__ Wh,          // [OF][K] bf16
    const float* __restrict__ dinv,
    unsigned char* __restrict__ G,          // fp8 e4m3, stride OF, value*S
    int N)
{
    constexpr int LDK = K + 8;
    constexpr int NT = OF / 16;             // MFMA col tiles
    constexpr int NSTEP = K / 32;
    __shared__ ushort Wlds[OF * LDK];

    const int tid = threadIdx.x;
    const int l = tid & 63;
    const int w = tid >> 6;                 // wave id: rows w*16..w*16+15
    const int m0 = blockIdx.x * 64;
    const int lm = l & 15, kg = l >> 4;

#pragma unroll
    for (int i = tid; i < OF * K / 8; i += 256) {
        int n = i / (K / 8), seg = i % (K / 8);
        *reinterpret_cast<uint4*>(&Wlds[n * LDK + seg * 8]) =
            *reinterpret_cast<const uint4*>(Wh + (long)n * K + seg * 8);
    }

    const float* xrf = nullptr;
    const ushort* xrb = nullptr;
    {
        int m = m0 + w * 16 + lm;
        if (m < N) {
            long r = nodes ? (long)nodes[m] : (long)m;
            if (XBF16) xrb = (const ushort*)Xv + r * (long)sx + kg * 8;
            else       xrf = (const float*)Xv + r * (long)sx + kg * 8;
        }
    }

    f32x4 acc[NT];
#pragma unroll
    for (int nt = 0; nt < NT; ++nt) acc[nt] = (f32x4){0.f, 0.f, 0.f, 0.f};

    __syncthreads();   // W staged; K-loop below is barrier-free

#pragma unroll
    for (int s = 0; s < NSTEP; ++s) {
        bf16x8 av = (bf16x8){0, 0, 0, 0, 0, 0, 0, 0};
        if (XBF16) {
            if (xrb) av = *reinterpret_cast<const bf16x8*>(xrb + s * 32);
        } else if (xrf) {
            float4 a0 = *reinterpret_cast<const float4*>(xrf + s * 32);
            float4 a1 = *reinterpret_cast<const float4*>(xrf + s * 32 + 4);
            av[0] = (short)f2bf(a0.x); av[1] = (short)f2bf(a0.y);
            av[2] = (short)f2bf(a0.z); av[3] = (short)f2bf(a0.w);
            av[4] = (short)f2bf(a1.x); av[5] = (short)f2bf(a1.y);
            av[6] = (short)f2bf(a1.z); av[7] = (short)f2bf(a1.w);
        }
#pragma unroll
        for (int nt = 0; nt < NT; ++nt) {
            bf16x8 bv = *reinterpret_cast<bf16x8*>(
                &Wlds[(nt * 16 + lm) * LDK + s * 32 + kg * 8]);
            acc[nt] = __builtin_amdgcn_mfma_f32_16x16x32_bf16(av, bv, acc[nt], 0, 0, 0);
        }
    }

#pragma unroll
    for (int r = 0; r < 4; ++r) {
        int m = m0 + w * 16 + kg * 4 + r;
        if (m < N) {
            float sc = dinv[m] * FP8_S;
#pragma unroll
            for (int nt = 0; nt < NT; ++nt)
                G[(long)m * OF + nt * 16 + lm] = f2fp8(acc[nt][r] * sc);
        }
    }
}

// ---------------------------------------------------------------------------
// CSR aggregation — fp8 payload, uint2 gather (8 fp8/lane, 1 line/edge).
// WPE = OF/8 lanes/edge; NPW nodes/wave; EPW = (64/NPW)/WPE = 4 -> full
// 8-deep pipeline at deg~32. 2 accumulator sets of float[8] (16 VGPR).
// f32 accumulate via HW cvt_pk; epilogue folds 1/S; optional bf16 output.
// ---------------------------------------------------------------------------
#define UNPK8(A, W)                                                        \
    {                                                                      \
        f32x2 _p0 = __builtin_amdgcn_cvt_pk_f32_fp8((int)(W).x, false);    \
        f32x2 _p1 = __builtin_amdgcn_cvt_pk_f32_fp8((int)(W).x, true);     \
        f32x2 _p2 = __builtin_amdgcn_cvt_pk_f32_fp8((int)(W).y, false);    \
        f32x2 _p3 = __builtin_amdgcn_cvt_pk_f32_fp8((int)(W).y, true);     \
        A[0] += _p0[0]; A[1] += _p0[1]; A[2] += _p1[0]; A[3] += _p1[1];    \
        A[4] += _p2[0]; A[5] += _p2[1]; A[6] += _p3[0]; A[7] += _p3[1];    \
    }

template <int OF, int OSTRIDE, bool YBF16, int NPW>
__global__ __launch_bounds__(256) void k_agg(
    const int* __restrict__ row_off, const int* __restrict__ esrc,
    const uint2* __restrict__ g,     // table row = OF/8 uint2 (OF fp8 bytes)
    const float* __restrict__ dinv, const float* __restrict__ b,
    void* __restrict__ y, int N)
{
    constexpr int LPN = 64 / NPW;    // lanes per node group
    constexpr int WPE = OF / 8;      // lanes per edge (uint2 each)
    constexpr int EPW = LPN / WPE;   // edges in parallel per node (= 4)
    static_assert(EPW == 4, "geometry: want EPW==4 for the 8-deep pipeline");
    const int lane = threadIdx.x & 63;
    const int grp = lane / LPN;      // node group within wave
    const int ll  = lane % LPN;
    const int q = ll % WPE;          // feature octet
    const int sub = ll / WPE;        // edge sub-slot 0..3
    const int wid = blockIdx.x * (blockDim.x >> 6) + (threadIdx.x >> 6);
    const int n = wid * NPW + grp;
    if (n >= N) return;
    const int start = row_off[n], end = row_off[n + 1];

    float a0[8], a1[8];
#pragma unroll
    for (int j = 0; j < 8; ++j) { a0[j] = 0.f; a1[j] = 0.f; }

    int e = start + sub;
    for (; e + 7 * EPW < end; e += 8 * EPW) {
        int s[8];
#pragma unroll
        for (int u = 0; u < 8; ++u) s[u] = esrc[e + u * EPW];
        uint2 w[8];
#pragma unroll
        for (int u = 0; u < 8; ++u) w[u] = g[(long)s[u] * WPE + q];
#pragma unroll
        for (int u = 0; u < 8; u += 2) { UNPK8(a0, w[u]); UNPK8(a1, w[u + 1]); }
    }
    for (; e + 3 * EPW < end; e += 4 * EPW) {
        int s[4];
#pragma unroll
        for (int u = 0; u < 4; ++u) s[u] = esrc[e + u * EPW];
        uint2 w[4];
#pragma unroll
        for (int u = 0; u < 4; ++u) w[u] = g[(long)s[u] * WPE + q];
        UNPK8(a0, w[0]); UNPK8(a1, w[1]); UNPK8(a0, w[2]); UNPK8(a1, w[3]);
    }
    for (; e < end; e += EPW) {
        uint2 w = g[(long)esrc[e] * WPE + q];
        UNPK8(a0, w);
    }

    float tot[8];
#pragma unroll
    for (int j = 0; j < 8; ++j) tot[j] = a0[j] + a1[j];
#pragma unroll
    for (int m = WPE; m < LPN; m <<= 1)   // group-local reduction
#pragma unroll
        for (int j = 0; j < 8; ++j) tot[j] += __shfl_xor(tot[j], m, 64);

    if (sub == 0) {
        uint2 sv = g[(long)n * WPE + q];   // self loop
        float sl[8] = {0.f, 0.f, 0.f, 0.f, 0.f, 0.f, 0.f, 0.f};
        UNPK8(sl, sv);
        float dvs = dinv[n] * (1.0f / FP8_S);
        float4 b0 = *reinterpret_cast<const float4*>(b + q * 8);
        float4 b1 = *reinterpret_cast<const float4*>(b + q * 8 + 4);
        float bb[8] = {b0.x, b0.y, b0.z, b0.w, b1.x, b1.y, b1.z, b1.w};
        float o[8];
#pragma unroll
        for (int j = 0; j < 8; ++j)
            o[j] = fmaxf(fmaf(tot[j] + sl[j], dvs, bb[j]), 0.f);
        if (YBF16) {
            uint4 ob;
            ob.x = (uint)f2bf(o[0]) | ((uint)f2bf(o[1]) << 16);
            ob.y = (uint)f2bf(o[2]) | ((uint)f2bf(o[3]) << 16);
            ob.z = (uint)f2bf(o[4]) | ((uint)f2bf(o[5]) << 16);
            ob.w = (uint)f2bf(o[6]) | ((uint)f2bf(o[7]) << 16);
            *reinterpret_cast<uint4*>((ushort*)y + (long)n * OSTRIDE + q * 8) = ob;
        } else {
            float4 o0 = {o[0], o[1], o[2], o[3]};
            float4 o1 = {o[4], o[5], o[6], o[7]};
            *reinterpret_cast<float4*>((float*)y + (long)n * OSTRIDE + q * 8) = o0;
            *reinterpret_cast<float4*>((float*)y + (long)n * OSTRIDE + q * 8 + 4) = o1;
        }
    }
}

extern "C" void kernel_launch(void* const* d_in, const int* in_sizes, int n_in,
                              void* d_out, int out_size, void* d_ws, size_t ws_size,
                              hipStream_t stream) {
    const int*   nodes = (const int*)d_in[0];
    const int*   edges = (const int*)d_in[1];
    const float* emb   = (const float*)d_in[2];
    const float* W1    = (const float*)d_in[3];
    const float* b1    = (const float*)d_in[4];
    const float* W2    = (const float*)d_in[5];
    const float* b2    = (const float*)d_in[6];
    const float* W3    = (const float*)d_in[7];
    const float* b3    = (const float*)d_in[8];

    const int N = in_sizes[0];
    const int E = in_sizes[1] / 2;
    const int* src  = edges;
    const int* dstv = edges + E;
    const int NB = (N + BNODES - 1) >> BSH;   // 196 for N=100000

    char* ws = (char*)d_ws;
    size_t off = 0;
    auto alloc = [&](size_t bytes) {
        char* p = ws + off;
        off += (bytes + 255) & ~(size_t)255;
        return p;
    };
    float* dinv    = (float*)alloc((size_t)N * 4);
    int*   row_off = (int*)  alloc((size_t)(N + 1) * 4);
    int*   bcnt    = (int*)  alloc((size_t)(NB + 1) * 4);
    int*   boff    = (int*)  alloc((size_t)(NB + 1) * 4);
    int*   bcur    = (int*)  alloc((size_t)NB * 4);
    int*   esrc    = (int*)  alloc((size_t)E * 4);
    char*  shared_region = alloc((size_t)E * 4);   // pairs u32 (12.8MB) / G1 fp8 (6.4MB)
    uint*  pairs   = (uint*)shared_region;
    unsigned char* G1 = (unsigned char*)shared_region;   // [N][64] fp8
    unsigned char* G2 = (unsigned char*)alloc((size_t)N * 32);
    unsigned char* G3 = (unsigned char*)alloc((size_t)N * 16);
    ushort* Xb     = (ushort*)alloc((size_t)N * 64 * 2);  // bf16 activations
    ushort* Wh1 = (ushort*)alloc(16384 * 2);
    ushort* Wh2 = (ushort*)alloc(2048 * 2);
    ushort* Wh3 = (ushort*)alloc(512 * 2);
    float* out     = (float*)d_out;

    // --- CSR build + dinv + W prep ---
    constexpr int CH = 8192;
    constexpr int HB = 1024;              // histogram blocks in k_pre
    const int nch = (E + CH - 1) / CH;
    hipMemsetAsync(bcnt, 0, (size_t)NB * 4, stream);
    hipLaunchKernelGGL(k_pre, dim3(HB + 74), dim3(256), 0, stream,
                       dstv, bcnt, E, HB, W1, W2, W3, Wh1, Wh2, Wh3);
    hipLaunchKernelGGL(k_bscan,  dim3(1), dim3(1024), 0, stream, bcnt, boff, bcur, NB);
    hipLaunchKernelGGL((k_part<CH>), dim3(nch), dim3(512), 0, stream,
                       src, dstv, bcur, pairs, E, NB);
    hipLaunchKernelGGL(k_bucket, dim3(NB), dim3(1024), 0, stream,
                       pairs, boff, row_off, dinv, esrc, N, NB, E);

    const int gb  = (N + 63) / 64;
    const int ab1 = (N + 7) / 8;    // NPW=2: 8 nodes/block
    const int ab2 = (N + 15) / 16;  // NPW=4: 16 nodes/block
    const int ab3 = (N + 31) / 32;  // NPW=8: 32 nodes/block

    // --- layer 1: 256 -> 64 ---  (G1 overwrites pairs; dead after k_bucket)
    hipLaunchKernelGGL((k_mfma<256, 64, false>), dim3(gb), dim3(256), 0, stream,
                       emb, 256, nodes, Wh1, dinv, G1, N);
    hipLaunchKernelGGL((k_agg<64, 64, true, 2>), dim3(ab1), dim3(256), 0, stream,
                       row_off, esrc, (const uint2*)G1, dinv, b1, Xb, N);
    // --- layer 2: 64 -> 32 ---
    hipLaunchKernelGGL((k_mfma<64, 32, true>), dim3(gb), dim3(256), 0, stream,
                       Xb, 64, (const int*)nullptr, Wh2, dinv, G2, N);
    hipLaunchKernelGGL((k_agg<32, 64, true, 4>), dim3(ab2), dim3(256), 0, stream,
                       row_off, esrc, (const uint2*)G2, dinv, b2, Xb, N);
    // --- layer 3: 32 -> 16 ---
    hipLaunchKernelGGL((k_mfma<32, 16, true>), dim3(gb), dim3(256), 0, stream,
                       Xb, 64, (const int*)nullptr, Wh3, dinv, G3, N);
    hipLaunchKernelGGL((k_agg<16, 16, false, 8>), dim3(ab3), dim3(256), 0, stream,
                       row_off, esrc, (const uint2*)G3, dinv, b3, out, N);
}

// Round 20
// 185.447 us; speedup vs baseline: 1.3514x; 1.1455x over previous
//
#include <hip/hip_runtime.h>

// ---------------------------------------------------------------------------
// 3-layer GCN forward. out[d] = relu( dinv[d]*( sum_{s->d} g[s] + g[d] ) + b ),
// g = (x@W)*dinv stored as OCP fp8 e4m3 scaled by S=256, row-major [N][OF].
// r20: CSR build shortened. Buckets get fixed stride CAP=20480 (32 sigma of
// Binomial(E,512/N)) in the pairs array, so k_part allocates via a zeroed
// global cursor -- the histogram pre-pass (k_pre) and k_bscan are DELETED.
// k_bucket derives its global edge base by reducing the 196 final cursors
// in-block. W bf16-transpose prep folded into k_part tail blocks.
// k_agg: uint2 fp8 gather, NPW-tuned EPW=4 8-deep pipeline (r18).
// k_mfma: barrier-free direct-A (r13). Xb bf16 (r14). Wave-scan sorts (r19).
// ---------------------------------------------------------------------------

#define BSH 9                 // 512 nodes per bucket
#define BNODES (1 << BSH)
#define BCAP 20480            // bucket capacity (mean 16384, sigma ~128)
#define FP8_S 256.0f          // message scale (e4m3: denorm<0.0156, max 448)

typedef __attribute__((ext_vector_type(8))) short bf16x8;
typedef __attribute__((ext_vector_type(4))) float f32x4;
typedef __attribute__((ext_vector_type(2))) float f32x2;

__device__ inline ushort f2bf(float x) {   // round-to-nearest-even f32->bf16
    uint u = __float_as_uint(x);
    return (ushort)((u + 0x7fffu + ((u >> 16) & 1u)) >> 16);
}
__device__ inline unsigned char f2fp8(float v) {   // f32 -> e4m3 (HW, RNE+sat)
    int p = __builtin_amdgcn_cvt_pk_fp8_f32(v, v, 0, false);
    return (unsigned char)(p & 0xff);
}
__device__ inline int wave_incl_scan(int v, int lane) {  // 64-lane inclusive
    int sc = v;
#pragma unroll
    for (int d = 1; d < 64; d <<= 1) {
        int u = __shfl_up(sc, d, 64);
        if (lane >= d) sc += u;
    }
    return sc;
}

// partition edges into CAP-strided buckets of packed (local_dst<<23 | src);
// LDS reorder for coalesced runs; global cursor allocation (no pre-histogram).
// Blocks >= nch do the W1/W2/W3 bf16 transpose prep instead.
template <int CH>
__global__ __launch_bounds__(512) void k_part(
    const int* __restrict__ src, const int* __restrict__ dst,
    int* __restrict__ bcur, uint* __restrict__ pairs, int E, int NB, int nch,
    const float* __restrict__ W1, const float* __restrict__ W2,
    const float* __restrict__ W3,
    ushort* __restrict__ Wh1, ushort* __restrict__ Wh2,
    ushort* __restrict__ Wh3)
{
    if ((int)blockIdx.x >= nch) {          // W prep tail blocks
        int i = (blockIdx.x - nch) * 512 + threadIdx.x;
        if (i < 16384) {                   // W1: 256x64
            int k = i >> 6, n = i & 63;
            Wh1[n * 256 + k] = f2bf(W1[i]);
        } else if (i < 16384 + 2048) {     // W2: 64x32
            int j = i - 16384;
            int k = j >> 5, n = j & 31;
            Wh2[n * 64 + k] = f2bf(W2[j]);
        } else if (i < 16384 + 2048 + 512) {  // W3: 32x16
            int j = i - 18432;
            int k = j >> 4, n = j & 15;
            Wh3[n * 32 + k] = f2bf(W3[j]);
        }
        return;
    }
    __shared__ uint sval[CH];
    __shared__ unsigned char sbid[CH];     // NB <= 256
    __shared__ int lh[256], lofs[256], lbase[256], cur[256];
    __shared__ int wsum[4];
    const int t = threadIdx.x;             // 0..511
    const int lane = t & 63, wv = t >> 6;
    const int e0 = blockIdx.x * CH;
    const int n = min(CH, E - e0);

    if (t < 256) { lh[t] = 0; cur[t] = 0; }
    __syncthreads();
    for (int i = t; i < n; i += 512) atomicAdd(&lh[dst[e0 + i] >> BSH], 1);
    __syncthreads();
    int v = 0, sc = 0;
    if (t < 256) {
        v = lh[t];
        sc = wave_incl_scan(v, lane);
        if (lane == 63) wsum[wv] = sc;
    }
    __syncthreads();
    if (t < 256) {
        int pre = 0;
#pragma unroll
        for (int w2 = 0; w2 < 4; ++w2) if (w2 < wv) pre += wsum[w2];
        lofs[t] = pre + sc - v;            // exclusive prefix within chunk
        if (v > 0) lbase[t] = atomicAdd(&bcur[t], v);  // global cursor (from 0)
    }
    __syncthreads();
    for (int i = t; i < n; i += 512) {
        int d = dst[e0 + i];
        int b = d >> BSH;
        int r = atomicAdd(&cur[b], 1);
        int slot = lofs[b] + r;
        sval[slot] = ((uint)(d & (BNODES - 1)) << 23) | (uint)src[e0 + i];
        sbid[slot] = (unsigned char)b;
    }
    __syncthreads();
    for (int i = t; i < n; i += 512) {
        int b = sbid[i];
        pairs[(long)b * BCAP + lbase[b] + (i - lofs[b])] = sval[i];
    }
}

// per-bucket: derive global edge base from final cursors, then per-node
// histogram + wave-scan, emit row_off/dinv, scatter esrc (compact layout).
__global__ __launch_bounds__(1024) void k_bucket(const uint* __restrict__ pairs,
                                                 const int* __restrict__ bcur,
                                                 int* __restrict__ row_off,
                                                 float* __restrict__ dinv,
                                                 int* __restrict__ esrc,
                                                 int N, int NB, int E) {
    __shared__ int cnt[BNODES];
    __shared__ int cur[BNODES];
    __shared__ int wsum[8];
    __shared__ int s_ebase;
    const int b = blockIdx.x;
    const int t = threadIdx.x;
    const int lane = t & 63, wv = t >> 6;
    const int base = b << BSH;
    const int nn = min(BNODES, N - base);
    const int mycnt = bcur[b];
    const long pbase = (long)b * BCAP;

    if (t == 0) s_ebase = 0;
    if (t < BNODES) cnt[t] = 0;
    __syncthreads();
    if (t < 256) {                         // sum of counts of buckets < b
        int contrib = (t < b && t < NB) ? bcur[t] : 0;
#pragma unroll
        for (int m = 1; m < 64; m <<= 1) contrib += __shfl_xor(contrib, m, 64);
        if (lane == 0 && contrib) atomicAdd(&s_ebase, contrib);
    }
    for (int e = t; e < mycnt; e += 1024)
        atomicAdd(&cnt[pairs[pbase + e] >> 23], 1);
    __syncthreads();
    const int ebase = s_ebase;
    int v = 0, sc = 0;
    if (t < BNODES) {
        v = cnt[t];
        sc = wave_incl_scan(v, lane);
        if (lane == 63) wsum[wv] = sc;
    }
    __syncthreads();
    if (t < nn) {
        int pre = 0;
#pragma unroll
        for (int w2 = 0; w2 < 8; ++w2) if (w2 < wv) pre += wsum[w2];
        int ex = pre + sc - v;             // exclusive prefix
        row_off[base + t] = ebase + ex;
        cur[t] = ex;
        dinv[base + t] = rsqrtf((float)(v + 1));
    }
    if (b == NB - 1 && t == 0) row_off[N] = E;
    __syncthreads();
    for (int e = t; e < mycnt; e += 1024) {
        uint p = pairs[pbase + e];
        int r = atomicAdd(&cur[p >> 23], 1);
        esrc[ebase + r] = (int)(p & 0x7fffffu);
    }
}

// ---------------------------------------------------------------------------
// Barrier-free direct-A MFMA GEMM (single-pass bf16):
// G[n][0..OF) = fp8( (X[row(n)] @ W) * dinv[n] * S ), row-major stride OF.
// XBF16: X is bf16 stride-sx (load fragment directly, no cvt).
// Block = 64 rows (4 waves x 16), W in LDS [OF][K+8] staged once.
// ---------------------------------------------------------------------------
template <int K, int OF, bool XBF16>
__global__ __launch_bounds__(256) void k_mfma(
    const void* __restrict__ Xv, int sx,
    const int* __restrict__ nodes,          // may be null (identity)
    const ushort* __restrict__ Wh,          // [OF][K] bf16
    const float* __restrict__ dinv,
    unsigned char* __restrict__ G,          // fp8 e4m3, stride OF, value*S
    int N)
{
    constexpr int LDK = K + 8;
    constexpr int NT = OF / 16;             // MFMA col tiles
    constexpr int NSTEP = K / 32;
    __shared__ ushort Wlds[OF * LDK];

    const int tid = threadIdx.x;
    const int l = tid & 63;
    const int w = tid >> 6;                 // wave id: rows w*16..w*16+15
    const int m0 = blockIdx.x * 64;
    const int lm = l & 15, kg = l >> 4;

#pragma unroll
    for (int i = tid; i < OF * K / 8; i += 256) {
        int n = i / (K / 8), seg = i % (K / 8);
        *reinterpret_cast<uint4*>(&Wlds[n * LDK + seg * 8]) =
            *reinterpret_cast<const uint4*>(Wh + (long)n * K + seg * 8);
    }

    const float* xrf = nullptr;
    const ushort* xrb = nullptr;
    {
        int m = m0 + w * 16 + lm;
        if (m < N) {
            long r = nodes ? (long)nodes[m] : (long)m;
            if (XBF16) xrb = (const ushort*)Xv + r * (long)sx + kg * 8;
            else       xrf = (const float*)Xv + r * (long)sx + kg * 8;
        }
    }

    f32x4 acc[NT];
#pragma unroll
    for (int nt = 0; nt < NT; ++nt) acc[nt] = (f32x4){0.f, 0.f, 0.f, 0.f};

    __syncthreads();   // W staged; K-loop below is barrier-free

#pragma unroll
    for (int s = 0; s < NSTEP; ++s) {
        bf16x8 av = (bf16x8){0, 0, 0, 0, 0, 0, 0, 0};
        if (XBF16) {
            if (xrb) av = *reinterpret_cast<const bf16x8*>(xrb + s * 32);
        } else if (xrf) {
            float4 a0 = *reinterpret_cast<const float4*>(xrf + s * 32);
            float4 a1 = *reinterpret_cast<const float4*>(xrf + s * 32 + 4);
            av[0] = (short)f2bf(a0.x); av[1] = (short)f2bf(a0.y);
            av[2] = (short)f2bf(a0.z); av[3] = (short)f2bf(a0.w);
            av[4] = (short)f2bf(a1.x); av[5] = (short)f2bf(a1.y);
            av[6] = (short)f2bf(a1.z); av[7] = (short)f2bf(a1.w);
        }
#pragma unroll
        for (int nt = 0; nt < NT; ++nt) {
            bf16x8 bv = *reinterpret_cast<bf16x8*>(
                &Wlds[(nt * 16 + lm) * LDK + s * 32 + kg * 8]);
            acc[nt] = __builtin_amdgcn_mfma_f32_16x16x32_bf16(av, bv, acc[nt], 0, 0, 0);
        }
    }

#pragma unroll
    for (int r = 0; r < 4; ++r) {
        int m = m0 + w * 16 + kg * 4 + r;
        if (m < N) {
            float sc = dinv[m] * FP8_S;
#pragma unroll
            for (int nt = 0; nt < NT; ++nt)
                G[(long)m * OF + nt * 16 + lm] = f2fp8(acc[nt][r] * sc);
        }
    }
}

// ---------------------------------------------------------------------------
// CSR aggregation — fp8 payload, uint2 gather (8 fp8/lane, 1 line/edge).
// WPE = OF/8 lanes/edge; NPW nodes/wave; EPW = (64/NPW)/WPE = 4 -> full
// 8-deep pipeline at deg~32. 2 accumulator sets of float[8] (16 VGPR).
// f32 accumulate via HW cvt_pk; epilogue folds 1/S; optional bf16 output.
// ---------------------------------------------------------------------------
#define UNPK8(A, W)                                                        \
    {                                                                      \
        f32x2 _p0 = __builtin_amdgcn_cvt_pk_f32_fp8((int)(W).x, false);    \
        f32x2 _p1 = __builtin_amdgcn_cvt_pk_f32_fp8((int)(W).x, true);     \
        f32x2 _p2 = __builtin_amdgcn_cvt_pk_f32_fp8((int)(W).y, false);    \
        f32x2 _p3 = __builtin_amdgcn_cvt_pk_f32_fp8((int)(W).y, true);     \
        A[0] += _p0[0]; A[1] += _p0[1]; A[2] += _p1[0]; A[3] += _p1[1];    \
        A[4] += _p2[0]; A[5] += _p2[1]; A[6] += _p3[0]; A[7] += _p3[1];    \
    }

template <int OF, int OSTRIDE, bool YBF16, int NPW>
__global__ __launch_bounds__(256) void k_agg(
    const int* __restrict__ row_off, const int* __restrict__ esrc,
    const uint2* __restrict__ g,     // table row = OF/8 uint2 (OF fp8 bytes)
    const float* __restrict__ dinv, const float* __restrict__ b,
    void* __restrict__ y, int N)
{
    constexpr int LPN = 64 / NPW;    // lanes per node group
    constexpr int WPE = OF / 8;      // lanes per edge (uint2 each)
    constexpr int EPW = LPN / WPE;   // edges in parallel per node (= 4)
    static_assert(EPW == 4, "geometry: want EPW==4 for the 8-deep pipeline");
    const int lane = threadIdx.x & 63;
    const int grp = lane / LPN;      // node group within wave
    const int ll  = lane % LPN;
    const int q = ll % WPE;          // feature octet
    const int sub = ll / WPE;        // edge sub-slot 0..3
    const int wid = blockIdx.x * (blockDim.x >> 6) + (threadIdx.x >> 6);
    const int n = wid * NPW + grp;
    if (n >= N) return;
    const int start = row_off[n], end = row_off[n + 1];

    float a0[8], a1[8];
#pragma unroll
    for (int j = 0; j < 8; ++j) { a0[j] = 0.f; a1[j] = 0.f; }

    int e = start + sub;
    for (; e + 7 * EPW < end; e += 8 * EPW) {
        int s[8];
#pragma unroll
        for (int u = 0; u < 8; ++u) s[u] = esrc[e + u * EPW];
        uint2 w[8];
#pragma unroll
        for (int u = 0; u < 8; ++u) w[u] = g[(long)s[u] * WPE + q];
#pragma unroll
        for (int u = 0; u < 8; u += 2) { UNPK8(a0, w[u]); UNPK8(a1, w[u + 1]); }
    }
    for (; e + 3 * EPW < end; e += 4 * EPW) {
        int s[4];
#pragma unroll
        for (int u = 0; u < 4; ++u) s[u] = esrc[e + u * EPW];
        uint2 w[4];
#pragma unroll
        for (int u = 0; u < 4; ++u) w[u] = g[(long)s[u] * WPE + q];
        UNPK8(a0, w[0]); UNPK8(a1, w[1]); UNPK8(a0, w[2]); UNPK8(a1, w[3]);
    }
    for (; e < end; e += EPW) {
        uint2 w = g[(long)esrc[e] * WPE + q];
        UNPK8(a0, w);
    }

    float tot[8];
#pragma unroll
    for (int j = 0; j < 8; ++j) tot[j] = a0[j] + a1[j];
#pragma unroll
    for (int m = WPE; m < LPN; m <<= 1)   // group-local reduction
#pragma unroll
        for (int j = 0; j < 8; ++j) tot[j] += __shfl_xor(tot[j], m, 64);

    if (sub == 0) {
        uint2 sv = g[(long)n * WPE + q];   // self loop
        float sl[8] = {0.f, 0.f, 0.f, 0.f, 0.f, 0.f, 0.f, 0.f};
        UNPK8(sl, sv);
        float dvs = dinv[n] * (1.0f / FP8_S);
        float4 b0 = *reinterpret_cast<const float4*>(b + q * 8);
        float4 b1 = *reinterpret_cast<const float4*>(b + q * 8 + 4);
        float bb[8] = {b0.x, b0.y, b0.z, b0.w, b1.x, b1.y, b1.z, b1.w};
        float o[8];
#pragma unroll
        for (int j = 0; j < 8; ++j)
            o[j] = fmaxf(fmaf(tot[j] + sl[j], dvs, bb[j]), 0.f);
        if (YBF16) {
            uint4 ob;
            ob.x = (uint)f2bf(o[0]) | ((uint)f2bf(o[1]) << 16);
            ob.y = (uint)f2bf(o[2]) | ((uint)f2bf(o[3]) << 16);
            ob.z = (uint)f2bf(o[4]) | ((uint)f2bf(o[5]) << 16);
            ob.w = (uint)f2bf(o[6]) | ((uint)f2bf(o[7]) << 16);
            *reinterpret_cast<uint4*>((ushort*)y + (long)n * OSTRIDE + q * 8) = ob;
        } else {
            float4 o0 = {o[0], o[1], o[2], o[3]};
            float4 o1 = {o[4], o[5], o[6], o[7]};
            *reinterpret_cast<float4*>((float*)y + (long)n * OSTRIDE + q * 8) = o0;
            *reinterpret_cast<float4*>((float*)y + (long)n * OSTRIDE + q * 8 + 4) = o1;
        }
    }
}

extern "C" void kernel_launch(void* const* d_in, const int* in_sizes, int n_in,
                              void* d_out, int out_size, void* d_ws, size_t ws_size,
                              hipStream_t stream) {
    const int*   nodes = (const int*)d_in[0];
    const int*   edges = (const int*)d_in[1];
    const float* emb   = (const float*)d_in[2];
    const float* W1    = (const float*)d_in[3];
    const float* b1    = (const float*)d_in[4];
    const float* W2    = (const float*)d_in[5];
    const float* b2    = (const float*)d_in[6];
    const float* W3    = (const float*)d_in[7];
    const float* b3    = (const float*)d_in[8];

    const int N = in_sizes[0];
    const int E = in_sizes[1] / 2;
    const int* src  = edges;
    const int* dstv = edges + E;
    const int NB = (N + BNODES - 1) >> BSH;   // 196 for N=100000

    char* ws = (char*)d_ws;
    size_t off = 0;
    auto alloc = [&](size_t bytes) {
        char* p = ws + off;
        off += (bytes + 255) & ~(size_t)255;
        return p;
    };
    float* dinv    = (float*)alloc((size_t)N * 4);
    int*   row_off = (int*)  alloc((size_t)(N + 1) * 4);
    int*   bcur    = (int*)  alloc((size_t)NB * 4);
    int*   esrc    = (int*)  alloc((size_t)E * 4);
    char*  shared_region = alloc((size_t)NB * BCAP * 4);  // pairs (15.3MB) ...
    uint*  pairs   = (uint*)shared_region;
    unsigned char* G1 = (unsigned char*)shared_region;    // ... aliases G1 fp8 (6.4MB)
    unsigned char* G2 = (unsigned char*)alloc((size_t)N * 32);
    unsigned char* G3 = (unsigned char*)alloc((size_t)N * 16);
    ushort* Xb     = (ushort*)alloc((size_t)N * 64 * 2);  // bf16 activations
    ushort* Wh1 = (ushort*)alloc(16384 * 2);
    ushort* Wh2 = (ushort*)alloc(2048 * 2);
    ushort* Wh3 = (ushort*)alloc(512 * 2);
    float* out     = (float*)d_out;

    // --- CSR build + dinv + W prep (no histogram pre-pass, no bucket scan) ---
    constexpr int CH = 8192;
    const int nch = (E + CH - 1) / CH;
    const int wblocks = (16384 + 2048 + 512 + 511) / 512;   // 37
    hipMemsetAsync(bcur, 0, (size_t)NB * 4, stream);
    hipLaunchKernelGGL((k_part<CH>), dim3(nch + wblocks), dim3(512), 0, stream,
                       src, dstv, bcur, pairs, E, NB, nch,
                       W1, W2, W3, Wh1, Wh2, Wh3);
    hipLaunchKernelGGL(k_bucket, dim3(NB), dim3(1024), 0, stream,
                       pairs, bcur, row_off, dinv, esrc, N, NB, E);

    const int gb  = (N + 63) / 64;
    const int ab1 = (N + 7) / 8;    // NPW=2: 8 nodes/block
    const int ab2 = (N + 15) / 16;  // NPW=4: 16 nodes/block
    const int ab3 = (N + 31) / 32;  // NPW=8: 32 nodes/block

    // --- layer 1: 256 -> 64 ---  (G1 overwrites pairs; dead after k_bucket)
    hipLaunchKernelGGL((k_mfma<256, 64, false>), dim3(gb), dim3(256), 0, stream,
                       emb, 256, nodes, Wh1, dinv, G1, N);
    hipLaunchKernelGGL((k_agg<64, 64, true, 2>), dim3(ab1), dim3(256), 0, stream,
                       row_off, esrc, (const uint2*)G1, dinv, b1, Xb, N);
    // --- layer 2: 64 -> 32 ---
    hipLaunchKernelGGL((k_mfma<64, 32, true>), dim3(gb), dim3(256), 0, stream,
                       Xb, 64, (const int*)nullptr, Wh2, dinv, G2, N);
    hipLaunchKernelGGL((k_agg<32, 64, true, 4>), dim3(ab2), dim3(256), 0, stream,
                       row_off, esrc, (const uint2*)G2, dinv, b2, Xb, N);
    // --- layer 3: 32 -> 16 ---
    hipLaunchKernelGGL((k_mfma<32, 16, true>), dim3(gb), dim3(256), 0, stream,
                       Xb, 64, (const int*)nullptr, Wh3, dinv, G3, N);
    hipLaunchKernelGGL((k_agg<16, 16, false, 8>), dim3(ab3), dim3(256), 0, stream,
                       row_off, esrc, (const uint2*)G3, dinv, b3, out, N);
}

// Round 21
// 182.741 us; speedup vs baseline: 1.3715x; 1.0148x over previous
//
#include <hip/hip_runtime.h>

// ---------------------------------------------------------------------------
// 3-layer GCN forward. out[d] = relu( dinv[d]*( sum_{s->d} g[s] + g[d] ) + b ),
// g = (x@W)*dinv stored as OCP fp8 e4m3 scaled by S=256, row-major [N][OF].
// r21: BSH 9->8 (256 nodes/bucket, NB=391). r20's k_bucket ran only 196
// blocks on 256 CUs (23% idle); 391 blocks rebalances. k_part adapted:
// 512-entry histogram/scan (8-wave scan), ushort sbid. k_bucket: 512 thr.
// CSR build: capacity-strided buckets, no histogram pre-pass (r20).
// k_agg: uint2 fp8 gather, NPW-tuned EPW=4 8-deep pipeline (r18).
// k_mfma: barrier-free direct-A (r13). Xb bf16 (r14).
// ---------------------------------------------------------------------------

#define BSH 8                 // 256 nodes per bucket
#define BNODES (1 << BSH)
#define BCAP 10240            // bucket capacity (mean 8192, sigma ~90)
#define FP8_S 256.0f          // message scale (e4m3: denorm<0.0156, max 448)

typedef __attribute__((ext_vector_type(8))) short bf16x8;
typedef __attribute__((ext_vector_type(4))) float f32x4;
typedef __attribute__((ext_vector_type(2))) float f32x2;

__device__ inline ushort f2bf(float x) {   // round-to-nearest-even f32->bf16
    uint u = __float_as_uint(x);
    return (ushort)((u + 0x7fffu + ((u >> 16) & 1u)) >> 16);
}
__device__ inline unsigned char f2fp8(float v) {   // f32 -> e4m3 (HW, RNE+sat)
    int p = __builtin_amdgcn_cvt_pk_fp8_f32(v, v, 0, false);
    return (unsigned char)(p & 0xff);
}
__device__ inline int wave_incl_scan(int v, int lane) {  // 64-lane inclusive
    int sc = v;
#pragma unroll
    for (int d = 1; d < 64; d <<= 1) {
        int u = __shfl_up(sc, d, 64);
        if (lane >= d) sc += u;
    }
    return sc;
}

// partition edges into CAP-strided buckets of packed (local_dst<<23 | src);
// LDS reorder for coalesced runs; global cursor allocation (no pre-histogram).
// Blocks >= nch do the W1/W2/W3 bf16 transpose prep instead.
template <int CH>
__global__ __launch_bounds__(512) void k_part(
    const int* __restrict__ src, const int* __restrict__ dst,
    int* __restrict__ bcur, uint* __restrict__ pairs, int E, int NB, int nch,
    const float* __restrict__ W1, const float* __restrict__ W2,
    const float* __restrict__ W3,
    ushort* __restrict__ Wh1, ushort* __restrict__ Wh2,
    ushort* __restrict__ Wh3)
{
    if ((int)blockIdx.x >= nch) {          // W prep tail blocks
        int i = (blockIdx.x - nch) * 512 + threadIdx.x;
        if (i < 16384) {                   // W1: 256x64
            int k = i >> 6, n = i & 63;
            Wh1[n * 256 + k] = f2bf(W1[i]);
        } else if (i < 16384 + 2048) {     // W2: 64x32
            int j = i - 16384;
            int k = j >> 5, n = j & 31;
            Wh2[n * 64 + k] = f2bf(W2[j]);
        } else if (i < 16384 + 2048 + 512) {  // W3: 32x16
            int j = i - 18432;
            int k = j >> 4, n = j & 15;
            Wh3[n * 32 + k] = f2bf(W3[j]);
        }
        return;
    }
    __shared__ uint sval[CH];
    __shared__ ushort sbid[CH];            // NB <= 512
    __shared__ int lh[512], lofs[512], lbase[512], cur[512];
    __shared__ int wsum[8];
    const int t = threadIdx.x;             // 0..511
    const int lane = t & 63, wv = t >> 6;
    const int e0 = blockIdx.x * CH;
    const int n = min(CH, E - e0);

    lh[t] = 0;
    cur[t] = 0;
    __syncthreads();
    for (int i = t; i < n; i += 512) atomicAdd(&lh[dst[e0 + i] >> BSH], 1);
    __syncthreads();
    int v = lh[t];
    int sc = wave_incl_scan(v, lane);
    if (lane == 63) wsum[wv] = sc;
    __syncthreads();
    {
        int pre = 0;
#pragma unroll
        for (int w2 = 0; w2 < 8; ++w2) if (w2 < wv) pre += wsum[w2];
        lofs[t] = pre + sc - v;            // exclusive prefix within chunk
        if (v > 0 && t < NB) lbase[t] = atomicAdd(&bcur[t], v);
    }
    __syncthreads();
    for (int i = t; i < n; i += 512) {
        int d = dst[e0 + i];
        int b = d >> BSH;
        int r = atomicAdd(&cur[b], 1);
        int slot = lofs[b] + r;
        sval[slot] = ((uint)(d & (BNODES - 1)) << 23) | (uint)src[e0 + i];
        sbid[slot] = (ushort)b;
    }
    __syncthreads();
    for (int i = t; i < n; i += 512) {
        int b = sbid[i];
        pairs[(long)b * BCAP + lbase[b] + (i - lofs[b])] = sval[i];
    }
}

// per-bucket: derive global edge base from final cursors, then per-node
// histogram + wave-scan, emit row_off/dinv, scatter esrc (compact layout).
__global__ __launch_bounds__(512) void k_bucket(const uint* __restrict__ pairs,
                                                const int* __restrict__ bcur,
                                                int* __restrict__ row_off,
                                                float* __restrict__ dinv,
                                                int* __restrict__ esrc,
                                                int N, int NB, int E) {
    __shared__ int cnt[BNODES];
    __shared__ int cur[BNODES];
    __shared__ int wsum[4];
    __shared__ int s_ebase;
    const int b = blockIdx.x;
    const int t = threadIdx.x;             // 0..511
    const int lane = t & 63, wv = t >> 6;
    const int base = b << BSH;
    const int nn = min(BNODES, N - base);
    const int mycnt = bcur[b];
    const long pbase = (long)b * BCAP;

    if (t == 0) s_ebase = 0;
    if (t < BNODES) cnt[t] = 0;
    __syncthreads();
    {                                      // sum of counts of buckets < b
        int contrib = (t < b && t < NB) ? bcur[t] : 0;
#pragma unroll
        for (int m = 1; m < 64; m <<= 1) contrib += __shfl_xor(contrib, m, 64);
        if (lane == 0 && contrib) atomicAdd(&s_ebase, contrib);
    }
    for (int e = t; e < mycnt; e += 512)
        atomicAdd(&cnt[pairs[pbase + e] >> 23], 1);
    __syncthreads();
    const int ebase = s_ebase;
    int v = 0, sc = 0;
    if (t < BNODES) {
        v = cnt[t];
        sc = wave_incl_scan(v, lane);
        if (lane == 63) wsum[wv] = sc;
    }
    __syncthreads();
    if (t < nn) {
        int pre = 0;
#pragma unroll
        for (int w2 = 0; w2 < 4; ++w2) if (w2 < wv) pre += wsum[w2];
        int ex = pre + sc - v;             // exclusive prefix
        row_off[base + t] = ebase + ex;
        cur[t] = ex;
        dinv[base + t] = rsqrtf((float)(v + 1));
    }
    if (b == NB - 1 && t == 0) row_off[N] = E;
    __syncthreads();
    for (int e = t; e < mycnt; e += 512) {
        uint p = pairs[pbase + e];
        int r = atomicAdd(&cur[p >> 23], 1);
        esrc[ebase + r] = (int)(p & 0x7fffffu);
    }
}

// ---------------------------------------------------------------------------
// Barrier-free direct-A MFMA GEMM (single-pass bf16):
// G[n][0..OF) = fp8( (X[row(n)] @ W) * dinv[n] * S ), row-major stride OF.
// XBF16: X is bf16 stride-sx (load fragment directly, no cvt).
// Block = 64 rows (4 waves x 16), W in LDS [OF][K+8] staged once.
// ---------------------------------------------------------------------------
template <int K, int OF, bool XBF16>
__global__ __launch_bounds__(256) void k_mfma(
    const void* __restrict__ Xv, int sx,
    const int* __restrict__ nodes,          // may be null (identity)
    const ushort* __restrict__ Wh,          // [OF][K] bf16
    const float* __restrict__ dinv,
    unsigned char* __restrict__ G,          // fp8 e4m3, stride OF, value*S
    int N)
{
    constexpr int LDK = K + 8;
    constexpr int NT = OF / 16;             // MFMA col tiles
    constexpr int NSTEP = K / 32;
    __shared__ ushort Wlds[OF * LDK];

    const int tid = threadIdx.x;
    const int l = tid & 63;
    const int w = tid >> 6;                 // wave id: rows w*16..w*16+15
    const int m0 = blockIdx.x * 64;
    const int lm = l & 15, kg = l >> 4;

#pragma unroll
    for (int i = tid; i < OF * K / 8; i += 256) {
        int n = i / (K / 8), seg = i % (K / 8);
        *reinterpret_cast<uint4*>(&Wlds[n * LDK + seg * 8]) =
            *reinterpret_cast<const uint4*>(Wh + (long)n * K + seg * 8);
    }

    const float* xrf = nullptr;
    const ushort* xrb = nullptr;
    {
        int m = m0 + w * 16 + lm;
        if (m < N) {
            long r = nodes ? (long)nodes[m] : (long)m;
            if (XBF16) xrb = (const ushort*)Xv + r * (long)sx + kg * 8;
            else       xrf = (const float*)Xv + r * (long)sx + kg * 8;
        }
    }

    f32x4 acc[NT];
#pragma unroll
    for (int nt = 0; nt < NT; ++nt) acc[nt] = (f32x4){0.f, 0.f, 0.f, 0.f};

    __syncthreads();   // W staged; K-loop below is barrier-free

#pragma unroll
    for (int s = 0; s < NSTEP; ++s) {
        bf16x8 av = (bf16x8){0, 0, 0, 0, 0, 0, 0, 0};
        if (XBF16) {
            if (xrb) av = *reinterpret_cast<const bf16x8*>(xrb + s * 32);
        } else if (xrf) {
            float4 a0 = *reinterpret_cast<const float4*>(xrf + s * 32);
            float4 a1 = *reinterpret_cast<const float4*>(xrf + s * 32 + 4);
            av[0] = (short)f2bf(a0.x); av[1] = (short)f2bf(a0.y);
            av[2] = (short)f2bf(a0.z); av[3] = (short)f2bf(a0.w);
            av[4] = (short)f2bf(a1.x); av[5] = (short)f2bf(a1.y);
            av[6] = (short)f2bf(a1.z); av[7] = (short)f2bf(a1.w);
        }
#pragma unroll
        for (int nt = 0; nt < NT; ++nt) {
            bf16x8 bv = *reinterpret_cast<bf16x8*>(
                &Wlds[(nt * 16 + lm) * LDK + s * 32 + kg * 8]);
            acc[nt] = __builtin_amdgcn_mfma_f32_16x16x32_bf16(av, bv, acc[nt], 0, 0, 0);
        }
    }

#pragma unroll
    for (int r = 0; r < 4; ++r) {
        int m = m0 + w * 16 + kg * 4 + r;
        if (m < N) {
            float sc = dinv[m] * FP8_S;
#pragma unroll
            for (int nt = 0; nt < NT; ++nt)
                G[(long)m * OF + nt * 16 + lm] = f2fp8(acc[nt][r] * sc);
        }
    }
}

// ---------------------------------------------------------------------------
// CSR aggregation — fp8 payload, uint2 gather (8 fp8/lane, 1 line/edge).
// WPE = OF/8 lanes/edge; NPW nodes/wave; EPW = (64/NPW)/WPE = 4 -> full
// 8-deep pipeline at deg~32. 2 accumulator sets of float[8] (16 VGPR).
// f32 accumulate via HW cvt_pk; epilogue folds 1/S; optional bf16 output.
// ---------------------------------------------------------------------------
#define UNPK8(A, W)                                                        \
    {                                                                      \
        f32x2 _p0 = __builtin_amdgcn_cvt_pk_f32_fp8((int)(W).x, false);    \
        f32x2 _p1 = __builtin_amdgcn_cvt_pk_f32_fp8((int)(W).x, true);     \
        f32x2 _p2 = __builtin_amdgcn_cvt_pk_f32_fp8((int)(W).y, false);    \
        f32x2 _p3 = __builtin_amdgcn_cvt_pk_f32_fp8((int)(W).y, true);     \
        A[0] += _p0[0]; A[1] += _p0[1]; A[2] += _p1[0]; A[3] += _p1[1];    \
        A[4] += _p2[0]; A[5] += _p2[1]; A[6] += _p3[0]; A[7] += _p3[1];    \
    }

template <int OF, int OSTRIDE, bool YBF16, int NPW>
__global__ __launch_bounds__(256) void k_agg(
    const int* __restrict__ row_off, const int* __restrict__ esrc,
    const uint2* __restrict__ g,     // table row = OF/8 uint2 (OF fp8 bytes)
    const float* __restrict__ dinv, const float* __restrict__ b,
    void* __restrict__ y, int N)
{
    constexpr int LPN = 64 / NPW;    // lanes per node group
    constexpr int WPE = OF / 8;      // lanes per edge (uint2 each)
    constexpr int EPW = LPN / WPE;   // edges in parallel per node (= 4)
    static_assert(EPW == 4, "geometry: want EPW==4 for the 8-deep pipeline");
    const int lane = threadIdx.x & 63;
    const int grp = lane / LPN;      // node group within wave
    const int ll  = lane % LPN;
    const int q = ll % WPE;          // feature octet
    const int sub = ll / WPE;        // edge sub-slot 0..3
    const int wid = blockIdx.x * (blockDim.x >> 6) + (threadIdx.x >> 6);
    const int n = wid * NPW + grp;
    if (n >= N) return;
    const int start = row_off[n], end = row_off[n + 1];

    float a0[8], a1[8];
#pragma unroll
    for (int j = 0; j < 8; ++j) { a0[j] = 0.f; a1[j] = 0.f; }

    int e = start + sub;
    for (; e + 7 * EPW < end; e += 8 * EPW) {
        int s[8];
#pragma unroll
        for (int u = 0; u < 8; ++u) s[u] = esrc[e + u * EPW];
        uint2 w[8];
#pragma unroll
        for (int u = 0; u < 8; ++u) w[u] = g[(long)s[u] * WPE + q];
#pragma unroll
        for (int u = 0; u < 8; u += 2) { UNPK8(a0, w[u]); UNPK8(a1, w[u + 1]); }
    }
    for (; e + 3 * EPW < end; e += 4 * EPW) {
        int s[4];
#pragma unroll
        for (int u = 0; u < 4; ++u) s[u] = esrc[e + u * EPW];
        uint2 w[4];
#pragma unroll
        for (int u = 0; u < 4; ++u) w[u] = g[(long)s[u] * WPE + q];
        UNPK8(a0, w[0]); UNPK8(a1, w[1]); UNPK8(a0, w[2]); UNPK8(a1, w[3]);
    }
    for (; e < end; e += EPW) {
        uint2 w = g[(long)esrc[e] * WPE + q];
        UNPK8(a0, w);
    }

    float tot[8];
#pragma unroll
    for (int j = 0; j < 8; ++j) tot[j] = a0[j] + a1[j];
#pragma unroll
    for (int m = WPE; m < LPN; m <<= 1)   // group-local reduction
#pragma unroll
        for (int j = 0; j < 8; ++j) tot[j] += __shfl_xor(tot[j], m, 64);

    if (sub == 0) {
        uint2 sv = g[(long)n * WPE + q];   // self loop
        float sl[8] = {0.f, 0.f, 0.f, 0.f, 0.f, 0.f, 0.f, 0.f};
        UNPK8(sl, sv);
        float dvs = dinv[n] * (1.0f / FP8_S);
        float4 b0 = *reinterpret_cast<const float4*>(b + q * 8);
        float4 b1 = *reinterpret_cast<const float4*>(b + q * 8 + 4);
        float bb[8] = {b0.x, b0.y, b0.z, b0.w, b1.x, b1.y, b1.z, b1.w};
        float o[8];
#pragma unroll
        for (int j = 0; j < 8; ++j)
            o[j] = fmaxf(fmaf(tot[j] + sl[j], dvs, bb[j]), 0.f);
        if (YBF16) {
            uint4 ob;
            ob.x = (uint)f2bf(o[0]) | ((uint)f2bf(o[1]) << 16);
            ob.y = (uint)f2bf(o[2]) | ((uint)f2bf(o[3]) << 16);
            ob.z = (uint)f2bf(o[4]) | ((uint)f2bf(o[5]) << 16);
            ob.w = (uint)f2bf(o[6]) | ((uint)f2bf(o[7]) << 16);
            *reinterpret_cast<uint4*>((ushort*)y + (long)n * OSTRIDE + q * 8) = ob;
        } else {
            float4 o0 = {o[0], o[1], o[2], o[3]};
            float4 o1 = {o[4], o[5], o[6], o[7]};
            *reinterpret_cast<float4*>((float*)y + (long)n * OSTRIDE + q * 8) = o0;
            *reinterpret_cast<float4*>((float*)y + (long)n * OSTRIDE + q * 8 + 4) = o1;
        }
    }
}

extern "C" void kernel_launch(void* const* d_in, const int* in_sizes, int n_in,
                              void* d_out, int out_size, void* d_ws, size_t ws_size,
                              hipStream_t stream) {
    const int*   nodes = (const int*)d_in[0];
    const int*   edges = (const int*)d_in[1];
    const float* emb   = (const float*)d_in[2];
    const float* W1    = (const float*)d_in[3];
    const float* b1    = (const float*)d_in[4];
    const float* W2    = (const float*)d_in[5];
    const float* b2    = (const float*)d_in[6];
    const float* W3    = (const float*)d_in[7];
    const float* b3    = (const float*)d_in[8];

    const int N = in_sizes[0];
    const int E = in_sizes[1] / 2;
    const int* src  = edges;
    const int* dstv = edges + E;
    const int NB = (N + BNODES - 1) >> BSH;   // 391 for N=100000

    char* ws = (char*)d_ws;
    size_t off = 0;
    auto alloc = [&](size_t bytes) {
        char* p = ws + off;
        off += (bytes + 255) & ~(size_t)255;
        return p;
    };
    float* dinv    = (float*)alloc((size_t)N * 4);
    int*   row_off = (int*)  alloc((size_t)(N + 1) * 4);
    int*   bcur    = (int*)  alloc((size_t)NB * 4);
    int*   esrc    = (int*)  alloc((size_t)E * 4);
    char*  shared_region = alloc((size_t)NB * BCAP * 4);  // pairs (16MB) ...
    uint*  pairs   = (uint*)shared_region;
    unsigned char* G1 = (unsigned char*)shared_region;    // ... aliases G1 fp8 (6.4MB)
    unsigned char* G2 = (unsigned char*)alloc((size_t)N * 32);
    unsigned char* G3 = (unsigned char*)alloc((size_t)N * 16);
    ushort* Xb     = (ushort*)alloc((size_t)N * 64 * 2);  // bf16 activations
    ushort* Wh1 = (ushort*)alloc(16384 * 2);
    ushort* Wh2 = (ushort*)alloc(2048 * 2);
    ushort* Wh3 = (ushort*)alloc(512 * 2);
    float* out     = (float*)d_out;

    // --- CSR build + dinv + W prep (no histogram pre-pass, no bucket scan) ---
    constexpr int CH = 8192;
    const int nch = (E + CH - 1) / CH;
    const int wblocks = (16384 + 2048 + 512 + 511) / 512;   // 37
    hipMemsetAsync(bcur, 0, (size_t)NB * 4, stream);
    hipLaunchKernelGGL((k_part<CH>), dim3(nch + wblocks), dim3(512), 0, stream,
                       src, dstv, bcur, pairs, E, NB, nch,
                       W1, W2, W3, Wh1, Wh2, Wh3);
    hipLaunchKernelGGL(k_bucket, dim3(NB), dim3(512), 0, stream,
                       pairs, bcur, row_off, dinv, esrc, N, NB, E);

    const int gb  = (N + 63) / 64;
    const int ab1 = (N + 7) / 8;    // NPW=2: 8 nodes/block
    const int ab2 = (N + 15) / 16;  // NPW=4: 16 nodes/block
    const int ab3 = (N + 31) / 32;  // NPW=8: 32 nodes/block

    // --- layer 1: 256 -> 64 ---  (G1 overwrites pairs; dead after k_bucket)
    hipLaunchKernelGGL((k_mfma<256, 64, false>), dim3(gb), dim3(256), 0, stream,
                       emb, 256, nodes, Wh1, dinv, G1, N);
    hipLaunchKernelGGL((k_agg<64, 64, true, 2>), dim3(ab1), dim3(256), 0, stream,
                       row_off, esrc, (const uint2*)G1, dinv, b1, Xb, N);
    // --- layer 2: 64 -> 32 ---
    hipLaunchKernelGGL((k_mfma<64, 32, true>), dim3(gb), dim3(256), 0, stream,
                       Xb, 64, (const int*)nullptr, Wh2, dinv, G2, N);
    hipLaunchKernelGGL((k_agg<32, 64, true, 4>), dim3(ab2), dim3(256), 0, stream,
                       row_off, esrc, (const uint2*)G2, dinv, b2, Xb, N);
    // --- layer 3: 32 -> 16 ---
    hipLaunchKernelGGL((k_mfma<32, 16, true>), dim3(gb), dim3(256), 0, stream,
                       Xb, 64, (const int*)nullptr, Wh3, dinv, G3, N);
    hipLaunchKernelGGL((k_agg<16, 16, false, 8>), dim3(ab3), dim3(256), 0, stream,
                       row_off, esrc, (const uint2*)G3, dinv, b3, out, N);
}

// Round 22
// 173.532 us; speedup vs baseline: 1.4442x; 1.0531x over previous
//
#include <hip/hip_runtime.h>

// ---------------------------------------------------------------------------
// 3-layer GCN forward. out[d] = relu( dinv[d]*( sum_{s->d} g[s] + g[d] ) + b ),
// g = (x@W)*dinv stored as OCP fp8 e4m3 scaled by S=256, row-major [N][OF].
// r22: micro-bundle. k_part int4 dst/src reads; k_bucket uint4 pairs reads;
// k_mfma explicit 1-step A-fragment register prefetch.
// CSR: capacity-strided buckets (r20), BSH=8 (r21), wave-scans (r19).
// k_agg: uint2 fp8 gather, NPW-tuned EPW=4 8-deep pipeline (r18).
// ---------------------------------------------------------------------------

#define BSH 8                 // 256 nodes per bucket
#define BNODES (1 << BSH)
#define BCAP 10240            // bucket capacity (mean 8192, sigma ~90)
#define FP8_S 256.0f          // message scale (e4m3: denorm<0.0156, max 448)

typedef __attribute__((ext_vector_type(8))) short bf16x8;
typedef __attribute__((ext_vector_type(4))) float f32x4;
typedef __attribute__((ext_vector_type(2))) float f32x2;

__device__ inline ushort f2bf(float x) {   // round-to-nearest-even f32->bf16
    uint u = __float_as_uint(x);
    return (ushort)((u + 0x7fffu + ((u >> 16) & 1u)) >> 16);
}
__device__ inline unsigned char f2fp8(float v) {   // f32 -> e4m3 (HW, RNE+sat)
    int p = __builtin_amdgcn_cvt_pk_fp8_f32(v, v, 0, false);
    return (unsigned char)(p & 0xff);
}
__device__ inline int wave_incl_scan(int v, int lane) {  // 64-lane inclusive
    int sc = v;
#pragma unroll
    for (int d = 1; d < 64; d <<= 1) {
        int u = __shfl_up(sc, d, 64);
        if (lane >= d) sc += u;
    }
    return sc;
}

// partition edges into CAP-strided buckets of packed (local_dst<<23 | src);
// LDS reorder for coalesced runs; global cursor allocation (no pre-histogram).
// Blocks >= nch do the W1/W2/W3 bf16 transpose prep instead.
template <int CH>
__global__ __launch_bounds__(512) void k_part(
    const int* __restrict__ src, const int* __restrict__ dst,
    int* __restrict__ bcur, uint* __restrict__ pairs, int E, int NB, int nch,
    const float* __restrict__ W1, const float* __restrict__ W2,
    const float* __restrict__ W3,
    ushort* __restrict__ Wh1, ushort* __restrict__ Wh2,
    ushort* __restrict__ Wh3)
{
    if ((int)blockIdx.x >= nch) {          // W prep tail blocks
        int i = (blockIdx.x - nch) * 512 + threadIdx.x;
        if (i < 16384) {                   // W1: 256x64
            int k = i >> 6, n = i & 63;
            Wh1[n * 256 + k] = f2bf(W1[i]);
        } else if (i < 16384 + 2048) {     // W2: 64x32
            int j = i - 16384;
            int k = j >> 5, n = j & 31;
            Wh2[n * 64 + k] = f2bf(W2[j]);
        } else if (i < 16384 + 2048 + 512) {  // W3: 32x16
            int j = i - 18432;
            int k = j >> 4, n = j & 15;
            Wh3[n * 32 + k] = f2bf(W3[j]);
        }
        return;
    }
    __shared__ uint sval[CH];
    __shared__ ushort sbid[CH];            // NB <= 512
    __shared__ int lh[512], lofs[512], lbase[512], cur[512];
    __shared__ int wsum[8];
    const int t = threadIdx.x;             // 0..511
    const int lane = t & 63, wv = t >> 6;
    const int e0 = blockIdx.x * CH;
    const int n = min(CH, E - e0);
    const int n4 = n & ~3;

    lh[t] = 0;
    cur[t] = 0;
    __syncthreads();
    // histogram pass (int4 reads)
    for (int i = t * 4; i < n4; i += 2048) {
        int4 d4 = *reinterpret_cast<const int4*>(dst + e0 + i);
        atomicAdd(&lh[d4.x >> BSH], 1);
        atomicAdd(&lh[d4.y >> BSH], 1);
        atomicAdd(&lh[d4.z >> BSH], 1);
        atomicAdd(&lh[d4.w >> BSH], 1);
    }
    for (int i = n4 + t; i < n; i += 512) atomicAdd(&lh[dst[e0 + i] >> BSH], 1);
    __syncthreads();
    int v = lh[t];
    int sc = wave_incl_scan(v, lane);
    if (lane == 63) wsum[wv] = sc;
    __syncthreads();
    {
        int pre = 0;
#pragma unroll
        for (int w2 = 0; w2 < 8; ++w2) if (w2 < wv) pre += wsum[w2];
        lofs[t] = pre + sc - v;            // exclusive prefix within chunk
        if (v > 0 && t < NB) lbase[t] = atomicAdd(&bcur[t], v);
    }
    __syncthreads();
    // bin pass (int4 reads of src+dst)
    for (int i = t * 4; i < n4; i += 2048) {
        int4 d4 = *reinterpret_cast<const int4*>(dst + e0 + i);
        int4 s4 = *reinterpret_cast<const int4*>(src + e0 + i);
        int dd[4] = {d4.x, d4.y, d4.z, d4.w};
        int ss[4] = {s4.x, s4.y, s4.z, s4.w};
#pragma unroll
        for (int u = 0; u < 4; ++u) {
            int b = dd[u] >> BSH;
            int r = atomicAdd(&cur[b], 1);
            int slot = lofs[b] + r;
            sval[slot] = ((uint)(dd[u] & (BNODES - 1)) << 23) | (uint)ss[u];
            sbid[slot] = (ushort)b;
        }
    }
    for (int i = n4 + t; i < n; i += 512) {
        int d = dst[e0 + i];
        int b = d >> BSH;
        int r = atomicAdd(&cur[b], 1);
        int slot = lofs[b] + r;
        sval[slot] = ((uint)(d & (BNODES - 1)) << 23) | (uint)src[e0 + i];
        sbid[slot] = (ushort)b;
    }
    __syncthreads();
    for (int i = t; i < n; i += 512) {
        int b = sbid[i];
        pairs[(long)b * BCAP + lbase[b] + (i - lofs[b])] = sval[i];
    }
}

// per-bucket: derive global edge base from final cursors, then per-node
// histogram + wave-scan, emit row_off/dinv, scatter esrc (compact layout).
__global__ __launch_bounds__(512) void k_bucket(const uint* __restrict__ pairs,
                                                const int* __restrict__ bcur,
                                                int* __restrict__ row_off,
                                                float* __restrict__ dinv,
                                                int* __restrict__ esrc,
                                                int N, int NB, int E) {
    __shared__ int cnt[BNODES];
    __shared__ int cur[BNODES];
    __shared__ int wsum[4];
    __shared__ int s_ebase;
    const int b = blockIdx.x;
    const int t = threadIdx.x;             // 0..511
    const int lane = t & 63, wv = t >> 6;
    const int base = b << BSH;
    const int nn = min(BNODES, N - base);
    const int mycnt = bcur[b];
    const int m4 = mycnt & ~3;
    const long pbase = (long)b * BCAP;

    if (t == 0) s_ebase = 0;
    if (t < BNODES) cnt[t] = 0;
    __syncthreads();
    {                                      // sum of counts of buckets < b
        int contrib = (t < b && t < NB) ? bcur[t] : 0;
#pragma unroll
        for (int m = 1; m < 64; m <<= 1) contrib += __shfl_xor(contrib, m, 64);
        if (lane == 0 && contrib) atomicAdd(&s_ebase, contrib);
    }
    // histogram (uint4 reads)
    for (int e = t * 4; e < m4; e += 2048) {
        uint4 p4 = *reinterpret_cast<const uint4*>(pairs + pbase + e);
        atomicAdd(&cnt[p4.x >> 23], 1);
        atomicAdd(&cnt[p4.y >> 23], 1);
        atomicAdd(&cnt[p4.z >> 23], 1);
        atomicAdd(&cnt[p4.w >> 23], 1);
    }
    for (int e = m4 + t; e < mycnt; e += 512)
        atomicAdd(&cnt[pairs[pbase + e] >> 23], 1);
    __syncthreads();
    const int ebase = s_ebase;
    int v = 0, sc = 0;
    if (t < BNODES) {
        v = cnt[t];
        sc = wave_incl_scan(v, lane);
        if (lane == 63) wsum[wv] = sc;
    }
    __syncthreads();
    if (t < nn) {
        int pre = 0;
#pragma unroll
        for (int w2 = 0; w2 < 4; ++w2) if (w2 < wv) pre += wsum[w2];
        int ex = pre + sc - v;             // exclusive prefix
        row_off[base + t] = ebase + ex;
        cur[t] = ex;
        dinv[base + t] = rsqrtf((float)(v + 1));
    }
    if (b == NB - 1 && t == 0) row_off[N] = E;
    __syncthreads();
    // scatter (uint4 reads)
    for (int e = t * 4; e < m4; e += 2048) {
        uint4 p4 = *reinterpret_cast<const uint4*>(pairs + pbase + e);
        uint pp[4] = {p4.x, p4.y, p4.z, p4.w};
#pragma unroll
        for (int u = 0; u < 4; ++u) {
            int r = atomicAdd(&cur[pp[u] >> 23], 1);
            esrc[ebase + r] = (int)(pp[u] & 0x7fffffu);
        }
    }
    for (int e = m4 + t; e < mycnt; e += 512) {
        uint p = pairs[pbase + e];
        int r = atomicAdd(&cur[p >> 23], 1);
        esrc[ebase + r] = (int)(p & 0x7fffffu);
    }
}

// ---------------------------------------------------------------------------
// Barrier-free direct-A MFMA GEMM (single-pass bf16), 1-step A prefetch:
// G[n][0..OF) = fp8( (X[row(n)] @ W) * dinv[n] * S ), row-major stride OF.
// Block = 64 rows (4 waves x 16), W in LDS [OF][K+8] staged once.
// ---------------------------------------------------------------------------
template <int K, int OF, bool XBF16>
__global__ __launch_bounds__(256) void k_mfma(
    const void* __restrict__ Xv, int sx,
    const int* __restrict__ nodes,          // may be null (identity)
    const ushort* __restrict__ Wh,          // [OF][K] bf16
    const float* __restrict__ dinv,
    unsigned char* __restrict__ G,          // fp8 e4m3, stride OF, value*S
    int N)
{
    constexpr int LDK = K + 8;
    constexpr int NT = OF / 16;             // MFMA col tiles
    constexpr int NSTEP = K / 32;
    __shared__ ushort Wlds[OF * LDK];

    const int tid = threadIdx.x;
    const int l = tid & 63;
    const int w = tid >> 6;                 // wave id: rows w*16..w*16+15
    const int m0 = blockIdx.x * 64;
    const int lm = l & 15, kg = l >> 4;

#pragma unroll
    for (int i = tid; i < OF * K / 8; i += 256) {
        int n = i / (K / 8), seg = i % (K / 8);
        *reinterpret_cast<uint4*>(&Wlds[n * LDK + seg * 8]) =
            *reinterpret_cast<const uint4*>(Wh + (long)n * K + seg * 8);
    }

    const float* xrf = nullptr;
    const ushort* xrb = nullptr;
    {
        int m = m0 + w * 16 + lm;
        if (m < N) {
            long r = nodes ? (long)nodes[m] : (long)m;
            if (XBF16) xrb = (const ushort*)Xv + r * (long)sx + kg * 8;
            else       xrf = (const float*)Xv + r * (long)sx + kg * 8;
        }
    }

    f32x4 acc[NT];
#pragma unroll
    for (int nt = 0; nt < NT; ++nt) acc[nt] = (f32x4){0.f, 0.f, 0.f, 0.f};

    // prefetch step 0
    float4 p0 = make_float4(0.f, 0.f, 0.f, 0.f), p1 = p0;
    bf16x8 pb = (bf16x8){0, 0, 0, 0, 0, 0, 0, 0};
    if (XBF16) {
        if (xrb) pb = *reinterpret_cast<const bf16x8*>(xrb);
    } else if (xrf) {
        p0 = *reinterpret_cast<const float4*>(xrf);
        p1 = *reinterpret_cast<const float4*>(xrf + 4);
    }

    __syncthreads();   // W staged; K-loop below is barrier-free

#pragma unroll
    for (int s = 0; s < NSTEP; ++s) {
        bf16x8 av;
        if (XBF16) {
            av = pb;
        } else {
            av[0] = (short)f2bf(p0.x); av[1] = (short)f2bf(p0.y);
            av[2] = (short)f2bf(p0.z); av[3] = (short)f2bf(p0.w);
            av[4] = (short)f2bf(p1.x); av[5] = (short)f2bf(p1.y);
            av[6] = (short)f2bf(p1.z); av[7] = (short)f2bf(p1.w);
        }
        if (s + 1 < NSTEP) {               // issue next step's loads early
            if (XBF16) {
                if (xrb) pb = *reinterpret_cast<const bf16x8*>(xrb + (s + 1) * 32);
            } else if (xrf) {
                p0 = *reinterpret_cast<const float4*>(xrf + (s + 1) * 32);
                p1 = *reinterpret_cast<const float4*>(xrf + (s + 1) * 32 + 4);
            }
        }
#pragma unroll
        for (int nt = 0; nt < NT; ++nt) {
            bf16x8 bv = *reinterpret_cast<bf16x8*>(
                &Wlds[(nt * 16 + lm) * LDK + s * 32 + kg * 8]);
            acc[nt] = __builtin_amdgcn_mfma_f32_16x16x32_bf16(av, bv, acc[nt], 0, 0, 0);
        }
    }

#pragma unroll
    for (int r = 0; r < 4; ++r) {
        int m = m0 + w * 16 + kg * 4 + r;
        if (m < N) {
            float sc = dinv[m] * FP8_S;
#pragma unroll
            for (int nt = 0; nt < NT; ++nt)
                G[(long)m * OF + nt * 16 + lm] = f2fp8(acc[nt][r] * sc);
        }
    }
}

// ---------------------------------------------------------------------------
// CSR aggregation — fp8 payload, uint2 gather (8 fp8/lane, 1 line/edge).
// WPE = OF/8 lanes/edge; NPW nodes/wave; EPW = (64/NPW)/WPE = 4 -> full
// 8-deep pipeline at deg~32. 2 accumulator sets of float[8] (16 VGPR).
// f32 accumulate via HW cvt_pk; epilogue folds 1/S; optional bf16 output.
// ---------------------------------------------------------------------------
#define UNPK8(A, W)                                                        \
    {                                                                      \
        f32x2 _p0 = __builtin_amdgcn_cvt_pk_f32_fp8((int)(W).x, false);    \
        f32x2 _p1 = __builtin_amdgcn_cvt_pk_f32_fp8((int)(W).x, true);     \
        f32x2 _p2 = __builtin_amdgcn_cvt_pk_f32_fp8((int)(W).y, false);    \
        f32x2 _p3 = __builtin_amdgcn_cvt_pk_f32_fp8((int)(W).y, true);     \
        A[0] += _p0[0]; A[1] += _p0[1]; A[2] += _p1[0]; A[3] += _p1[1];    \
        A[4] += _p2[0]; A[5] += _p2[1]; A[6] += _p3[0]; A[7] += _p3[1];    \
    }

template <int OF, int OSTRIDE, bool YBF16, int NPW>
__global__ __launch_bounds__(256) void k_agg(
    const int* __restrict__ row_off, const int* __restrict__ esrc,
    const uint2* __restrict__ g,     // table row = OF/8 uint2 (OF fp8 bytes)
    const float* __restrict__ dinv, const float* __restrict__ b,
    void* __restrict__ y, int N)
{
    constexpr int LPN = 64 / NPW;    // lanes per node group
    constexpr int WPE = OF / 8;      // lanes per edge (uint2 each)
    constexpr int EPW = LPN / WPE;   // edges in parallel per node (= 4)
    static_assert(EPW == 4, "geometry: want EPW==4 for the 8-deep pipeline");
    const int lane = threadIdx.x & 63;
    const int grp = lane / LPN;      // node group within wave
    const int ll  = lane % LPN;
    const int q = ll % WPE;          // feature octet
    const int sub = ll / WPE;        // edge sub-slot 0..3
    const int wid = blockIdx.x * (blockDim.x >> 6) + (threadIdx.x >> 6);
    const int n = wid * NPW + grp;
    if (n >= N) return;
    const int start = row_off[n], end = row_off[n + 1];

    float a0[8], a1[8];
#pragma unroll
    for (int j = 0; j < 8; ++j) { a0[j] = 0.f; a1[j] = 0.f; }

    int e = start + sub;
    for (; e + 7 * EPW < end; e += 8 * EPW) {
        int s[8];
#pragma unroll
        for (int u = 0; u < 8; ++u) s[u] = esrc[e + u * EPW];
        uint2 w[8];
#pragma unroll
        for (int u = 0; u < 8; ++u) w[u] = g[(long)s[u] * WPE + q];
#pragma unroll
        for (int u = 0; u < 8; u += 2) { UNPK8(a0, w[u]); UNPK8(a1, w[u + 1]); }
    }
    for (; e + 3 * EPW < end; e += 4 * EPW) {
        int s[4];
#pragma unroll
        for (int u = 0; u < 4; ++u) s[u] = esrc[e + u * EPW];
        uint2 w[4];
#pragma unroll
        for (int u = 0; u < 4; ++u) w[u] = g[(long)s[u] * WPE + q];
        UNPK8(a0, w[0]); UNPK8(a1, w[1]); UNPK8(a0, w[2]); UNPK8(a1, w[3]);
    }
    for (; e < end; e += EPW) {
        uint2 w = g[(long)esrc[e] * WPE + q];
        UNPK8(a0, w);
    }

    float tot[8];
#pragma unroll
    for (int j = 0; j < 8; ++j) tot[j] = a0[j] + a1[j];
#pragma unroll
    for (int m = WPE; m < LPN; m <<= 1)   // group-local reduction
#pragma unroll
        for (int j = 0; j < 8; ++j) tot[j] += __shfl_xor(tot[j], m, 64);

    if (sub == 0) {
        uint2 sv = g[(long)n * WPE + q];   // self loop
        float sl[8] = {0.f, 0.f, 0.f, 0.f, 0.f, 0.f, 0.f, 0.f};
        UNPK8(sl, sv);
        float dvs = dinv[n] * (1.0f / FP8_S);
        float4 b0 = *reinterpret_cast<const float4*>(b + q * 8);
        float4 b1 = *reinterpret_cast<const float4*>(b + q * 8 + 4);
        float bb[8] = {b0.x, b0.y, b0.z, b0.w, b1.x, b1.y, b1.z, b1.w};
        float o[8];
#pragma unroll
        for (int j = 0; j < 8; ++j)
            o[j] = fmaxf(fmaf(tot[j] + sl[j], dvs, bb[j]), 0.f);
        if (YBF16) {
            uint4 ob;
            ob.x = (uint)f2bf(o[0]) | ((uint)f2bf(o[1]) << 16);
            ob.y = (uint)f2bf(o[2]) | ((uint)f2bf(o[3]) << 16);
            ob.z = (uint)f2bf(o[4]) | ((uint)f2bf(o[5]) << 16);
            ob.w = (uint)f2bf(o[6]) | ((uint)f2bf(o[7]) << 16);
            *reinterpret_cast<uint4*>((ushort*)y + (long)n * OSTRIDE + q * 8) = ob;
        } else {
            float4 o0 = {o[0], o[1], o[2], o[3]};
            float4 o1 = {o[4], o[5], o[6], o[7]};
            *reinterpret_cast<float4*>((float*)y + (long)n * OSTRIDE + q * 8) = o0;
            *reinterpret_cast<float4*>((float*)y + (long)n * OSTRIDE + q * 8 + 4) = o1;
        }
    }
}

extern "C" void kernel_launch(void* const* d_in, const int* in_sizes, int n_in,
                              void* d_out, int out_size, void* d_ws, size_t ws_size,
                              hipStream_t stream) {
    const int*   nodes = (const int*)d_in[0];
    const int*   edges = (const int*)d_in[1];
    const float* emb   = (const float*)d_in[2];
    const float* W1    = (const float*)d_in[3];
    const float* b1    = (const float*)d_in[4];
    const float* W2    = (const float*)d_in[5];
    const float* b2    = (const float*)d_in[6];
    const float* W3    = (const float*)d_in[7];
    const float* b3    = (const float*)d_in[8];

    const int N = in_sizes[0];
    const int E = in_sizes[1] / 2;
    const int* src  = edges;
    const int* dstv = edges + E;
    const int NB = (N + BNODES - 1) >> BSH;   // 391 for N=100000

    char* ws = (char*)d_ws;
    size_t off = 0;
    auto alloc = [&](size_t bytes) {
        char* p = ws + off;
        off += (bytes + 255) & ~(size_t)255;
        return p;
    };
    float* dinv    = (float*)alloc((size_t)N * 4);
    int*   row_off = (int*)  alloc((size_t)(N + 1) * 4);
    int*   bcur    = (int*)  alloc((size_t)NB * 4);
    int*   esrc    = (int*)  alloc((size_t)E * 4);
    char*  shared_region = alloc((size_t)NB * BCAP * 4);  // pairs (16MB) ...
    uint*  pairs   = (uint*)shared_region;
    unsigned char* G1 = (unsigned char*)shared_region;    // ... aliases G1 fp8 (6.4MB)
    unsigned char* G2 = (unsigned char*)alloc((size_t)N * 32);
    unsigned char* G3 = (unsigned char*)alloc((size_t)N * 16);
    ushort* Xb     = (ushort*)alloc((size_t)N * 64 * 2);  // bf16 activations
    ushort* Wh1 = (ushort*)alloc(16384 * 2);
    ushort* Wh2 = (ushort*)alloc(2048 * 2);
    ushort* Wh3 = (ushort*)alloc(512 * 2);
    float* out     = (float*)d_out;

    // --- CSR build + dinv + W prep (no histogram pre-pass, no bucket scan) ---
    constexpr int CH = 8192;
    const int nch = (E + CH - 1) / CH;
    const int wblocks = (16384 + 2048 + 512 + 511) / 512;   // 37
    hipMemsetAsync(bcur, 0, (size_t)NB * 4, stream);
    hipLaunchKernelGGL((k_part<CH>), dim3(nch + wblocks), dim3(512), 0, stream,
                       src, dstv, bcur, pairs, E, NB, nch,
                       W1, W2, W3, Wh1, Wh2, Wh3);
    hipLaunchKernelGGL(k_bucket, dim3(NB), dim3(512), 0, stream,
                       pairs, bcur, row_off, dinv, esrc, N, NB, E);

    const int gb  = (N + 63) / 64;
    const int ab1 = (N + 7) / 8;    // NPW=2: 8 nodes/block
    const int ab2 = (N + 15) / 16;  // NPW=4: 16 nodes/block
    const int ab3 = (N + 31) / 32;  // NPW=8: 32 nodes/block

    // --- layer 1: 256 -> 64 ---  (G1 overwrites pairs; dead after k_bucket)
    hipLaunchKernelGGL((k_mfma<256, 64, false>), dim3(gb), dim3(256), 0, stream,
                       emb, 256, nodes, Wh1, dinv, G1, N);
    hipLaunchKernelGGL((k_agg<64, 64, true, 2>), dim3(ab1), dim3(256), 0, stream,
                       row_off, esrc, (const uint2*)G1, dinv, b1, Xb, N);
    // --- layer 2: 64 -> 32 ---
    hipLaunchKernelGGL((k_mfma<64, 32, true>), dim3(gb), dim3(256), 0, stream,
                       Xb, 64, (const int*)nullptr, Wh2, dinv, G2, N);
    hipLaunchKernelGGL((k_agg<32, 64, true, 4>), dim3(ab2), dim3(256), 0, stream,
                       row_off, esrc, (const uint2*)G2, dinv, b2, Xb, N);
    // --- layer 3: 32 -> 16 ---
    hipLaunchKernelGGL((k_mfma<32, 16, true>), dim3(gb), dim3(256), 0, stream,
                       Xb, 64, (const int*)nullptr, Wh3, dinv, G3, N);
    hipLaunchKernelGGL((k_agg<16, 16, false, 8>), dim3(ab3), dim3(256), 0, stream,
                       row_off, esrc, (const uint2*)G3, dinv, b3, out, N);
}